// Round 1
// baseline (259.202 us; speedup 1.0000x reference)
//
#include <hip/hip_runtime.h>
#include <hip/hip_bf16.h>
#include <stdint.h>

// ---------------- common types / helpers ----------------
typedef __attribute__((ext_vector_type(8))) short short8v;   // 8 x bf16 (4 VGPRs)
typedef __attribute__((ext_vector_type(4))) float floatx4;

#define DEV __device__ __forceinline__

DEV ushort f2bf(float f) {                      // RNE float -> bf16 bits
  union { float f; unsigned u; } v; v.f = f;
  unsigned r = v.u + 0x7fffu + ((v.u >> 16) & 1u);
  return (ushort)(r >> 16);
}
DEV float bf2f(ushort b) {
  union { unsigned u; float f; } v; v.u = ((unsigned)b) << 16;
  return v.f;
}
// XOR swizzle for 64-col bf16 tiles (128B rows): spreads the 16-lane
// row-walk across 8 distinct 16B slots (16-way conflict -> 2-way, free).
DEV int swz(int row, int colByte) {
  return row * 128 + (colByte ^ ((row & 7) << 4));
}
DEV floatx4 mfma16(short8v a, short8v b, floatx4 c) {
  return __builtin_amdgcn_mfma_f32_16x16x32_bf16(a, b, c, 0, 0, 0);
}

#define GLD_LDS16(g, l)                                                   \
  __builtin_amdgcn_global_load_lds(                                       \
      (const __attribute__((address_space(1))) void*)(g),                 \
      (__attribute__((address_space(3))) void*)(l), 16, 0, 0)

// problem constants
constexpr int Bc = 8, HEADS = 8, NTOK = 4096, CDIM = 512, DH = 64;
constexpr float SCALE = 0.125f;   // DH^-0.5

// ---------------- fp32 -> bf16 convert ----------------
__global__ void k_f2bf(const float* __restrict__ src, ushort* __restrict__ dst, int n4) {
  int i = blockIdx.x * blockDim.x + threadIdx.x;
  int stride = gridDim.x * blockDim.x;
  for (int j = i; j < n4; j += stride) {
    float4 f = ((const float4*)src)[j];
    ushort4 o;
    o.x = f2bf(f.x); o.y = f2bf(f.y); o.z = f2bf(f.z); o.w = f2bf(f.w);
    ((ushort4*)dst)[j] = o;
  }
}

// ---------------- bf16 MFMA GEMM: C[M,N] = A[M,K] @ B[N,K]^T (+bias) ----------------
// 128x128 tile, BK=64, 4 waves (2x2 of 64x64), 16x16x32 bf16 MFMA.
template <bool OUT_BF16, bool HAS_BIAS>
__global__ __launch_bounds__(256) void k_gemm_bt(const ushort* __restrict__ A,
                                                 const ushort* __restrict__ Bm,
                                                 void* __restrict__ Cout,
                                                 const float* __restrict__ bias,
                                                 int M, int N, int K) {
  __shared__ ushort sA[128 * 64];
  __shared__ ushort sB[128 * 64];
  const int t = threadIdx.x;
  const int w = t >> 6, l = t & 63;
  const int lg = l >> 4, li = l & 15;
  const int m0 = blockIdx.y * 128, n0 = blockIdx.x * 128;
  const int wr = (w >> 1) * 64, wc = (w & 1) * 64;
  floatx4 acc[4][4] = {};
  const int nkt = K >> 6;
  for (int kt = 0; kt < nkt; ++kt) {
    __syncthreads();
    // stage A,B tiles (16B per lane per issue, source pre-swizzled so the
    // linear LDS dest holds the swizzled layout)
#pragma unroll
    for (int i = 0; i < 4; ++i) {
      int flat = i * 256 + t;
      int row = flat >> 3, pch = flat & 7;
      int sch = pch ^ (row & 7);
      const ushort* ga = A + (size_t)(m0 + row) * K + kt * 64 + sch * 8;
      GLD_LDS16(ga, (char*)sA + flat * 16);
    }
#pragma unroll
    for (int i = 0; i < 4; ++i) {
      int flat = i * 256 + t;
      int row = flat >> 3, pch = flat & 7;
      int sch = pch ^ (row & 7);
      const ushort* gb = Bm + (size_t)(n0 + row) * K + kt * 64 + sch * 8;
      GLD_LDS16(gb, (char*)sB + flat * 16);
    }
    __syncthreads();
#pragma unroll
    for (int kk = 0; kk < 2; ++kk) {
      int colb = (kk * 32 + lg * 8) * 2;
      short8v af[4], bf[4];
#pragma unroll
      for (int m = 0; m < 4; ++m) {
        int row = wr + m * 16 + li;
        af[m] = *(const short8v*)((const char*)sA + swz(row, colb));
      }
#pragma unroll
      for (int n = 0; n < 4; ++n) {
        int row = wc + n * 16 + li;
        bf[n] = *(const short8v*)((const char*)sB + swz(row, colb));
      }
#pragma unroll
      for (int m = 0; m < 4; ++m)
#pragma unroll
        for (int n = 0; n < 4; ++n)
          acc[m][n] = mfma16(af[m], bf[n], acc[m][n]);
    }
  }
  // epilogue: D frag layout col=lane&15, row=(lane>>4)*4+r (verified layout)
#pragma unroll
  for (int m = 0; m < 4; ++m)
#pragma unroll
    for (int n = 0; n < 4; ++n) {
      int col = n0 + wc + n * 16 + li;
      float bv = HAS_BIAS ? bias[col] : 0.f;
#pragma unroll
      for (int r = 0; r < 4; ++r) {
        int row = m0 + wr + m * 16 + lg * 4 + r;
        float v = acc[m][n][r] + bv;
        if (OUT_BF16)
          ((ushort*)Cout)[(size_t)row * N + col] = f2bf(v);
        else
          ((float*)Cout)[(size_t)row * N + col] = v;
      }
    }
}

// ---------------- adaptive 8x8 pool: rep[b,q,c] = mean of 64 tokens ----------------
__global__ __launch_bounds__(256) void k_pool(const ushort* __restrict__ wm,
                                              float* __restrict__ rep) {
  const int blk = blockIdx.x;      // b*64 + qi
  const int b = blk >> 6, qi = blk & 63;
  const int ph = qi >> 3, pw = qi & 7;
  const int c0 = threadIdx.x * 2;
  float a0 = 0.f, a1 = 0.f;
  for (int u = 0; u < 64; ++u) {
    int n = (ph * 8 + (u >> 3)) * 64 + pw * 8 + (u & 7);
    unsigned v = *(const unsigned*)(wm + ((size_t)b * NTOK + n) * CDIM + c0);
    a0 += bf2f((ushort)(v & 0xffff));
    a1 += bf2f((ushort)(v >> 16));
  }
  float* dst = rep + ((size_t)b * 64 + qi) * CDIM + c0;
  dst[0] = a0 * 0.015625f;
  dst[1] = a1 * 0.015625f;
}

// ---------------- per-(b,h) attention ----------------
// One block (4 waves) per (b,h). Two passes over 64-key chunks:
// pass1 row-max; pass2 exp/sum + attnT write (unnormalized) + PV MFMA.
// Then reph update, 64x64 self-attn, xd = step_x/rowsum * (attn2 @ reph_new).
__global__ __launch_bounds__(256) void k_attn(const ushort* __restrict__ wmat,
                                              const float* __restrict__ rep,
                                              const float* __restrict__ step_rep,
                                              const float* __restrict__ step_x,
                                              ushort* __restrict__ attnT,  // [bh,4096,64]
                                              ushort* __restrict__ xd) {   // [bh,64,64]
  __shared__ char smem[49664] __attribute__((aligned(128)));
  ushort* sQ = (ushort*)smem;                 // [64 q][64 d]   8KB (swizzled)
  ushort* sK = (ushort*)(smem + 8192);        // [64 n][64 d]   8KB (swizzled)
  ushort* sV = (ushort*)(smem + 16384);       // [64 d][64 n]   8KB (swizzled)
  ushort* sP = (ushort*)(smem + 24576);       // [64 q][64 n]   8KB (swizzled)
  float* sSum = (float*)(smem + 32768);       // [64]
  float* sR = (float*)(smem + 33024);         // [64][65] fp32 reph_new
  float* sT = (float*)(smem + 8192);          // [64][65] reuse sK/sV/sP after PV

  const int bh = blockIdx.x;
  const int b = bh >> 3, h = bh & 7;
  const int t = threadIdx.x, w = t >> 6, l = t & 63;
  const int lg = l >> 4, li = l & 15;
  const ushort* wbase = wmat + (size_t)b * NTOK * CDIM + h * DH;

  // Q = rep head slice -> bf16 swizzled LDS
  {
    int q = t >> 2, d0 = (t & 3) * 16;
    const float* src = rep + ((size_t)b * 64 + q) * CDIM + h * DH + d0;
    ushort tmp[16] __attribute__((aligned(16)));
#pragma unroll
    for (int j = 0; j < 16; ++j) tmp[j] = f2bf(src[j]);
    *(short8v*)((char*)sQ + swz(q, d0 * 2)) = *(short8v*)&tmp[0];
    *(short8v*)((char*)sQ + swz(q, d0 * 2 + 16)) = *(short8v*)&tmp[8];
  }
  __syncthreads();

  // hoist Q A-frags (wave w owns q rows w*16..w*16+15)
  short8v qa[2];
#pragma unroll
  for (int kk = 0; kk < 2; ++kk)
    qa[kk] = *(const short8v*)((const char*)sQ + swz(w * 16 + li, (kk * 32 + lg * 8) * 2));

  // ---- pass 1: row max ----
  float rmax[4] = {-1e30f, -1e30f, -1e30f, -1e30f};
  for (int c = 0; c < 64; ++c) {
    __syncthreads();
    {
      int n = t >> 2, d0 = (t & 3) * 16;
      const ushort* g = wbase + (size_t)(c * 64 + n) * CDIM + d0;
      *(short8v*)((char*)sK + swz(n, d0 * 2)) = *(const short8v*)g;
      *(short8v*)((char*)sK + swz(n, d0 * 2 + 16)) = *(const short8v*)(g + 8);
    }
    __syncthreads();
    floatx4 s[4] = {};
#pragma unroll
    for (int kk = 0; kk < 2; ++kk) {
      int colb = (kk * 32 + lg * 8) * 2;
#pragma unroll
      for (int nf = 0; nf < 4; ++nf) {
        short8v bf = *(const short8v*)((const char*)sK + swz(nf * 16 + li, colb));
        s[nf] = mfma16(qa[kk], bf, s[nf]);
      }
    }
#pragma unroll
    for (int r = 0; r < 4; ++r) {
      float mx = fmaxf(fmaxf(s[0][r], s[1][r]), fmaxf(s[2][r], s[3][r]));
      rmax[r] = fmaxf(rmax[r], mx);
    }
  }
#pragma unroll
  for (int r = 0; r < 4; ++r) {
    float v = rmax[r];
    for (int mask = 1; mask < 16; mask <<= 1) v = fmaxf(v, __shfl_xor(v, mask));
    rmax[r] = v * SCALE;   // softmax operates on scaled dots
  }

  // ---- pass 2: exp/sum, attnT, PV ----
  float rsum[4] = {};
  floatx4 pv[4] = {};
  for (int c = 0; c < 64; ++c) {
    __syncthreads();
    {
      int n = t >> 2, d0 = (t & 3) * 16;
      const ushort* g = wbase + (size_t)(c * 64 + n) * CDIM + d0;
      *(short8v*)((char*)sK + swz(n, d0 * 2)) = *(const short8v*)g;
      *(short8v*)((char*)sK + swz(n, d0 * 2 + 16)) = *(const short8v*)(g + 8);
    }
    {
      // transpose-stage V: wave w stages d rows w*16..w*16+15
      const ushort* g = wbase + (size_t)(c * 64 + l) * CDIM + w * 16;
      short8v v0 = *(const short8v*)g;
      short8v v1 = *(const short8v*)(g + 8);
#pragma unroll
      for (int j = 0; j < 8; ++j) {
        *(ushort*)((char*)sV + swz(w * 16 + j, l * 2)) = (ushort)v0[j];
        *(ushort*)((char*)sV + swz(w * 16 + 8 + j, l * 2)) = (ushort)v1[j];
      }
    }
    __syncthreads();
    floatx4 s[4] = {};
#pragma unroll
    for (int kk = 0; kk < 2; ++kk) {
      int colb = (kk * 32 + lg * 8) * 2;
#pragma unroll
      for (int nf = 0; nf < 4; ++nf) {
        short8v bf = *(const short8v*)((const char*)sK + swz(nf * 16 + li, colb));
        s[nf] = mfma16(qa[kk], bf, s[nf]);
      }
    }
#pragma unroll
    for (int nf = 0; nf < 4; ++nf) {
      ushort pb[4];
#pragma unroll
      for (int r = 0; r < 4; ++r) {
        float p = __expf(s[nf][r] * SCALE - rmax[r]);
        rsum[r] += p;
        pb[r] = f2bf(p);
        int qrow = w * 16 + lg * 4 + r;
        *(ushort*)((char*)sP + swz(qrow, (nf * 16 + li) * 2)) = pb[r];
      }
      int key = c * 64 + nf * 16 + li;
      ushort4 pk; pk.x = pb[0]; pk.y = pb[1]; pk.z = pb[2]; pk.w = pb[3];
      *(ushort4*)(attnT + ((size_t)bh * NTOK + key) * 64 + w * 16 + lg * 4) = pk;
    }
    // PV: rep_delta_wave[16 q, 64 d] += P[16,64] @ V[64,64]
#pragma unroll
    for (int kk = 0; kk < 2; ++kk) {
      int colb = (kk * 32 + lg * 8) * 2;
      short8v pa = *(const short8v*)((const char*)sP + swz(w * 16 + li, colb));
#pragma unroll
      for (int nf = 0; nf < 4; ++nf) {
        short8v vb = *(const short8v*)((const char*)sV + swz(nf * 16 + li, colb));
        pv[nf] = mfma16(pa, vb, pv[nf]);
      }
    }
  }

  // row sums
#pragma unroll
  for (int r = 0; r < 4; ++r) {
    float v = rsum[r];
    for (int mask = 1; mask < 16; mask <<= 1) v += __shfl_xor(v, mask);
    rsum[r] = v;
  }
  if (li == 0) {
#pragma unroll
    for (int r = 0; r < 4; ++r) sSum[w * 16 + lg * 4 + r] = rsum[r];
  }
  // reph_new = rep + step_rep * rep_delta  (normalize PV by rowsum)
  {
    float srep = step_rep[h];
#pragma unroll
    for (int nf = 0; nf < 4; ++nf)
#pragma unroll
      for (int r = 0; r < 4; ++r) {
        int qrow = w * 16 + lg * 4 + r, d = nf * 16 + li;
        float base = rep[((size_t)b * 64 + qrow) * CDIM + h * DH + d];
        sR[qrow * 65 + d] = base + srep * (pv[nf][r] / rsum[r]);
      }
  }
  __syncthreads();

  // tiny self-attn: dots2 = reph_new @ reph_new^T * SCALE, softmax -> sT
  {
    int q = t >> 2, jb = (t & 3) * 16;
    float a[16];
#pragma unroll
    for (int j = 0; j < 16; ++j) {
      float accd = 0.f;
      for (int d = 0; d < 64; ++d) accd += sR[q * 65 + d] * sR[(jb + j) * 65 + d];
      a[j] = accd * SCALE;
    }
    float mx = a[0];
#pragma unroll
    for (int j = 1; j < 16; ++j) mx = fmaxf(mx, a[j]);
    mx = fmaxf(mx, __shfl_xor(mx, 1));
    mx = fmaxf(mx, __shfl_xor(mx, 2));
    float sm = 0.f;
#pragma unroll
    for (int j = 0; j < 16; ++j) { a[j] = __expf(a[j] - mx); sm += a[j]; }
    sm += __shfl_xor(sm, 1);
    sm += __shfl_xor(sm, 2);
    float inv = 1.f / sm;
#pragma unroll
    for (int j = 0; j < 16; ++j) sT[q * 65 + jb + j] = a[j] * inv;
  }
  __syncthreads();
  // x_delta = attn2 @ reph_new; fold step_x and 1/rowsum (for the reused attn)
  {
    int q = t >> 2, db = (t & 3) * 16;
    float accd[16] = {};
    for (int j = 0; j < 64; ++j) {
      float w2 = sT[q * 65 + j];
#pragma unroll
      for (int d = 0; d < 16; ++d) accd[d] += w2 * sR[j * 65 + db + d];
    }
    float sc = step_x[h] / sSum[q];
    ushort o[16] __attribute__((aligned(16)));
#pragma unroll
    for (int d = 0; d < 16; ++d) o[d] = f2bf(accd[d] * sc);
    ushort* dst = xd + ((size_t)bh * 64 + q) * 64 + db;
    *(short8v*)dst = *(short8v*)&o[0];
    *(short8v*)(dst + 8) = *(short8v*)&o[8];
  }
}

// ---------------- upsample: xdt[b,n,h*64+d] = sum_q attnT[bh,n,q]*xd[bh,q,d] ----------------
__global__ __launch_bounds__(256) void k_upsample(const ushort* __restrict__ attnT,
                                                  const ushort* __restrict__ xd,
                                                  ushort* __restrict__ xdt) {
  __shared__ ushort sXT[64 * 64];   // [d][q] swizzled
  const int bh = blockIdx.y, mblk = blockIdx.x;
  const int b = bh >> 3, h = bh & 7;
  const int t = threadIdx.x, w = t >> 6, l = t & 63;
  const int lg = l >> 4, li = l & 15;
  {
    const ushort* g = xd + ((size_t)bh * 64 + l) * 64 + w * 16;
    short8v v0 = *(const short8v*)g;
    short8v v1 = *(const short8v*)(g + 8);
#pragma unroll
    for (int j = 0; j < 8; ++j) {
      *(ushort*)((char*)sXT + swz(w * 16 + j, l * 2)) = (ushort)v0[j];
      *(ushort*)((char*)sXT + swz(w * 16 + 8 + j, l * 2)) = (ushort)v1[j];
    }
  }
  __syncthreads();
  const int nbase = mblk * 256 + w * 64;
  floatx4 acc[4][4] = {};
#pragma unroll
  for (int kk = 0; kk < 2; ++kk) {
    int kb = kk * 32 + lg * 8;
    short8v bfr[4];
#pragma unroll
    for (int nf = 0; nf < 4; ++nf)
      bfr[nf] = *(const short8v*)((const char*)sXT + swz(nf * 16 + li, kb * 2));
#pragma unroll
    for (int m = 0; m < 4; ++m) {
      const ushort* ga = attnT + ((size_t)bh * NTOK + nbase + m * 16 + li) * 64 + kb;
      short8v af = *(const short8v*)ga;
#pragma unroll
      for (int nf = 0; nf < 4; ++nf) acc[m][nf] = mfma16(af, bfr[nf], acc[m][nf]);
    }
  }
#pragma unroll
  for (int m = 0; m < 4; ++m)
#pragma unroll
    for (int nf = 0; nf < 4; ++nf)
#pragma unroll
      for (int r = 0; r < 4; ++r) {
        int row = nbase + m * 16 + lg * 4 + r;
        int col = h * DH + nf * 16 + li;
        xdt[((size_t)b * NTOK + row) * CDIM + col] = f2bf(acc[m][nf][r]);
      }
}

// ---------------- launch ----------------
extern "C" void kernel_launch(void* const* d_in, const int* in_sizes, int n_in,
                              void* d_out, int out_size, void* d_ws, size_t ws_size,
                              hipStream_t stream) {
  const float* x = (const float*)d_in[0];
  const float* proj_w = (const float*)d_in[1];
  const float* step_rep = (const float*)d_in[2];
  const float* step_x = (const float*)d_in[3];
  const float* to_out_w = (const float*)d_in[4];
  const float* to_out_b = (const float*)d_in[5];
  float* out = (float*)d_out;
  char* ws = (char*)d_ws;

  // workspace layout (with reuse):
  ushort* bufA = (ushort*)(ws);                  // x_bf16  -> attnT   (32 MiB)
  ushort* bufB = (ushort*)(ws + 33554432);       // w_bf16  -> xdt     (32 MiB)
  ushort* pw   = (ushort*)(ws + 67108864);       // proj_w bf16 (512 KiB)
  ushort* tow  = (ushort*)(ws + 67633152);       // to_out_w bf16 (512 KiB)
  float*  rep  = (float*)(ws + 68157440);        // pooled rep fp32 (1 MiB)
  ushort* xd   = (ushort*)(ws + 69206016);       // xd bf16 (512 KiB)

  k_f2bf<<<2048, 256, 0, stream>>>(x, bufA, (Bc * NTOK * CDIM) / 4);
  k_f2bf<<<256, 256, 0, stream>>>(proj_w, pw, (CDIM * CDIM) / 4);
  k_f2bf<<<256, 256, 0, stream>>>(to_out_w, tow, (CDIM * CDIM) / 4);

  k_gemm_bt<true, false><<<dim3(CDIM / 128, (Bc * NTOK) / 128), 256, 0, stream>>>(
      bufA, pw, bufB, nullptr, Bc * NTOK, CDIM, CDIM);

  k_pool<<<Bc * 64, 256, 0, stream>>>(bufB, rep);

  k_attn<<<Bc * HEADS, 256, 0, stream>>>(bufB, rep, step_rep, step_x, bufA, xd);

  k_upsample<<<dim3(NTOK / 256, Bc * HEADS), 256, 0, stream>>>(bufA, xd, bufB);

  k_gemm_bt<false, true><<<dim3(CDIM / 128, (Bc * NTOK) / 128), 256, 0, stream>>>(
      bufB, tow, out, to_out_b, Bc * NTOK, CDIM, CDIM);
}

// Round 2
// 156.308 us; speedup vs baseline: 1.6583x; 1.6583x over previous
//
#include <hip/hip_runtime.h>
#include <hip/hip_bf16.h>
#include <stdint.h>

// ---------------- common types / helpers ----------------
typedef __attribute__((ext_vector_type(8))) short short8v;   // 8 x bf16 (4 VGPRs)
typedef __attribute__((ext_vector_type(4))) float floatx4;

#define DEV __device__ __forceinline__

DEV ushort f2bf(float f) {                      // RNE float -> bf16 bits
  union { float f; unsigned u; } v; v.f = f;
  unsigned r = v.u + 0x7fffu + ((v.u >> 16) & 1u);
  return (ushort)(r >> 16);
}
DEV float bf2f(ushort b) {
  union { unsigned u; float f; } v; v.u = ((unsigned)b) << 16;
  return v.f;
}
// XOR swizzle for 64-col bf16 tiles (128B rows)
DEV int swz(int row, int colByte) {
  return row * 128 + (colByte ^ ((row & 7) << 4));
}
// XOR swizzle for 128-col bf16 tiles (256B rows)
DEV int swz256(int row, int colByte) {
  return row * 256 + (colByte ^ ((row & 7) << 4));
}
DEV floatx4 mfma16(short8v a, short8v b, floatx4 c) {
  return __builtin_amdgcn_mfma_f32_16x16x32_bf16(a, b, c, 0, 0, 0);
}

#define GLD_LDS16(g, l)                                                   \
  __builtin_amdgcn_global_load_lds(                                       \
      (const __attribute__((address_space(1))) void*)(g),                 \
      (__attribute__((address_space(3))) void*)(l), 16, 0, 0)

// problem constants
constexpr int Bc = 8, HEADS = 8, NTOK = 4096, CDIM = 512, DH = 64;
constexpr float SCALE = 0.125f;   // DH^-0.5
constexpr int NCH = 32, CHK = 128;   // key chunks for qkexp

// ---------------- fp32 -> bf16 convert ----------------
__global__ void k_f2bf(const float* __restrict__ src, ushort* __restrict__ dst, int n4) {
  int i = blockIdx.x * blockDim.x + threadIdx.x;
  int stride = gridDim.x * blockDim.x;
  for (int j = i; j < n4; j += stride) {
    float4 f = ((const float4*)src)[j];
    ushort4 o;
    o.x = f2bf(f.x); o.y = f2bf(f.y); o.z = f2bf(f.z); o.w = f2bf(f.w);
    ((ushort4*)dst)[j] = o;
  }
}

// ---------------- bf16 MFMA GEMM: C[M,N] = A[M,K] @ B[N,K]^T (+bias) ----------------
template <bool OUT_BF16, bool HAS_BIAS>
__global__ __launch_bounds__(256) void k_gemm_bt(const ushort* __restrict__ A,
                                                 const ushort* __restrict__ Bm,
                                                 void* __restrict__ Cout,
                                                 const float* __restrict__ bias,
                                                 int M, int N, int K) {
  __shared__ ushort sA[128 * 64];
  __shared__ ushort sB[128 * 64];
  const int t = threadIdx.x;
  const int w = t >> 6, l = t & 63;
  const int lg = l >> 4, li = l & 15;
  const int m0 = blockIdx.y * 128, n0 = blockIdx.x * 128;
  const int wr = (w >> 1) * 64, wc = (w & 1) * 64;
  floatx4 acc[4][4] = {};
  const int nkt = K >> 6;
  for (int kt = 0; kt < nkt; ++kt) {
    __syncthreads();
#pragma unroll
    for (int i = 0; i < 4; ++i) {
      int flat = i * 256 + t;
      int row = flat >> 3, pch = flat & 7;
      int sch = pch ^ (row & 7);
      const ushort* ga = A + (size_t)(m0 + row) * K + kt * 64 + sch * 8;
      GLD_LDS16(ga, (char*)sA + flat * 16);
    }
#pragma unroll
    for (int i = 0; i < 4; ++i) {
      int flat = i * 256 + t;
      int row = flat >> 3, pch = flat & 7;
      int sch = pch ^ (row & 7);
      const ushort* gb = Bm + (size_t)(n0 + row) * K + kt * 64 + sch * 8;
      GLD_LDS16(gb, (char*)sB + flat * 16);
    }
    __syncthreads();
#pragma unroll
    for (int kk = 0; kk < 2; ++kk) {
      int colb = (kk * 32 + lg * 8) * 2;
      short8v af[4], bf[4];
#pragma unroll
      for (int m = 0; m < 4; ++m) {
        int row = wr + m * 16 + li;
        af[m] = *(const short8v*)((const char*)sA + swz(row, colb));
      }
#pragma unroll
      for (int n = 0; n < 4; ++n) {
        int row = wc + n * 16 + li;
        bf[n] = *(const short8v*)((const char*)sB + swz(row, colb));
      }
#pragma unroll
      for (int m = 0; m < 4; ++m)
#pragma unroll
        for (int n = 0; n < 4; ++n)
          acc[m][n] = mfma16(af[m], bf[n], acc[m][n]);
    }
  }
#pragma unroll
  for (int m = 0; m < 4; ++m)
#pragma unroll
    for (int n = 0; n < 4; ++n) {
      int col = n0 + wc + n * 16 + li;
      float bv = HAS_BIAS ? bias[col] : 0.f;
#pragma unroll
      for (int r = 0; r < 4; ++r) {
        int row = m0 + wr + m * 16 + lg * 4 + r;
        float v = acc[m][n][r] + bv;
        if (OUT_BF16)
          ((ushort*)Cout)[(size_t)row * N + col] = f2bf(v);
        else
          ((float*)Cout)[(size_t)row * N + col] = v;
      }
    }
}

// ---------------- adaptive 8x8 pool + pre-swizzled bf16 Q tiles ----------------
__global__ __launch_bounds__(256) void k_pool(const ushort* __restrict__ wm,
                                              float* __restrict__ rep,
                                              ushort* __restrict__ qbf) {
  const int blk = blockIdx.x;      // b*64 + qi
  const int b = blk >> 6, qi = blk & 63;
  const int ph = qi >> 3, pw = qi & 7;
  const int c0 = threadIdx.x * 2;
  float a0 = 0.f, a1 = 0.f;
  for (int u = 0; u < 64; ++u) {
    int n = (ph * 8 + (u >> 3)) * 64 + pw * 8 + (u & 7);
    unsigned v = *(const unsigned*)(wm + ((size_t)b * NTOK + n) * CDIM + c0);
    a0 += bf2f((ushort)(v & 0xffff));
    a1 += bf2f((ushort)(v >> 16));
  }
  a0 *= 0.015625f; a1 *= 0.015625f;
  float* dst = rep + ((size_t)b * 64 + qi) * CDIM + c0;
  dst[0] = a0;
  dst[1] = a1;
  // bf16 Q tile, swizzled layout per (b,h): [64 q][64 d]
  int h = c0 >> 6, d0 = c0 & 63;   // d0 even
  unsigned pack = (unsigned)f2bf(a0) | ((unsigned)f2bf(a1) << 16);
  *(unsigned*)((char*)qbf + ((size_t)(b * 8 + h)) * 8192 + swz(qi, d0 * 2)) = pack;
}

// ---------------- qkexp: per (bh, chunk of 128 keys) ----------------
// dots = Q@K^T, P = exp(dots*SCALE) (no max-sub; dots bounded ~1),
// write P^T to attnT[bh,n,q], partial rowsum -> rsumP, partial PV -> pvP.
__global__ __launch_bounds__(256) void k_qkexp(const ushort* __restrict__ wmat,
                                               const ushort* __restrict__ qbf,
                                               ushort* __restrict__ attnT,  // [bh,4096,64]
                                               float* __restrict__ pvP,     // [bh,32,64,64]
                                               float* __restrict__ rsumP) { // [bh,32,64]
  __shared__ char smem[57344] __attribute__((aligned(128)));
  ushort* sQ  = (ushort*)smem;            // [64 q][64 d]   8KB swizzled
  ushort* sK  = (ushort*)(smem + 8192);   // [128 n][64 d] 16KB swizzled
  ushort* sVT = (ushort*)(smem + 24576);  // [64 d][128 n] 16KB swizzled (256B rows)
  ushort* sP  = (ushort*)(smem + 40960);  // [64 q][128 k] 16KB swizzled (256B rows)

  const int bh = blockIdx.y, ch = blockIdx.x;
  const int b = bh >> 3, h = bh & 7;
  const int t = threadIdx.x, w = t >> 6, l = t & 63;
  const int lg = l >> 4, li = l & 15;
  const ushort* wbase = wmat + ((size_t)b * NTOK + ch * CHK) * CDIM + h * DH;

  // stage Q (pre-swizzled in qbf -> linear copy)
  {
    const char* qsrc = (const char*)(qbf + (size_t)bh * 4096);
#pragma unroll
    for (int i = 0; i < 2; ++i) {
      int flat = i * 256 + t;
      GLD_LDS16(qsrc + flat * 16, (char*)sQ + flat * 16);
    }
  }
  // stage K tile (source pre-swizzled)
#pragma unroll
  for (int i = 0; i < 4; ++i) {
    int flat = i * 256 + t;
    int row = flat >> 3, pch = flat & 7;
    int sch = pch ^ (row & 7);
    GLD_LDS16(wbase + (size_t)row * CDIM + sch * 8, (char*)sK + flat * 16);
  }
  // stage V transposed: [d][n]
  {
    int n = t & 127, dh2 = (t >> 7) * 32;
    const ushort* g = wbase + (size_t)n * CDIM + dh2;
#pragma unroll
    for (int j = 0; j < 4; ++j) {
      short8v v = *(const short8v*)(g + j * 8);
#pragma unroll
      for (int e = 0; e < 8; ++e) {
        int d = dh2 + j * 8 + e;
        *(ushort*)((char*)sVT + swz256(d, 2 * n)) = (ushort)v[e];
      }
    }
  }
  __syncthreads();

  // Q A-frags (wave w owns q rows w*16..w*16+15)
  short8v qa[2];
#pragma unroll
  for (int kk = 0; kk < 2; ++kk)
    qa[kk] = *(const short8v*)((const char*)sQ + swz(w * 16 + li, (kk * 32 + lg * 8) * 2));

  // QK^T: s[kf] = [16 q x 16 k] frag, kf over 128 keys
  floatx4 s[8] = {};
#pragma unroll
  for (int kk = 0; kk < 2; ++kk) {
    int cb = (kk * 32 + lg * 8) * 2;
#pragma unroll
    for (int kf = 0; kf < 8; ++kf) {
      short8v kb = *(const short8v*)((const char*)sK + swz(kf * 16 + li, cb));
      s[kf] = mfma16(qa[kk], kb, s[kf]);
    }
  }

  // exp, rowsum partial, attnT store, sP write
  float rs[4] = {};
#pragma unroll
  for (int kf = 0; kf < 8; ++kf) {
    ushort pb[4];
#pragma unroll
    for (int r = 0; r < 4; ++r) {
      float p = __expf(s[kf][r] * SCALE);
      rs[r] += p;
      pb[r] = f2bf(p);
      int q = w * 16 + lg * 4 + r;
      *(ushort*)((char*)sP + swz256(q, (kf * 16 + li) * 2)) = pb[r];
    }
    int key = ch * CHK + kf * 16 + li;
    ushort4 pk; pk.x = pb[0]; pk.y = pb[1]; pk.z = pb[2]; pk.w = pb[3];
    *(ushort4*)(attnT + ((size_t)bh * NTOK + key) * 64 + w * 16 + lg * 4) = pk;
  }
#pragma unroll
  for (int r = 0; r < 4; ++r) {
    float v = rs[r];
    for (int mask = 1; mask < 16; mask <<= 1) v += __shfl_xor(v, mask);
    if (li == 0) rsumP[((size_t)bh * NCH + ch) * 64 + w * 16 + lg * 4 + r] = v;
  }

  // PV partial: pv[16 q x 64 d] per wave, contraction over 128 keys
  floatx4 pv[4] = {};
#pragma unroll
  for (int kk4 = 0; kk4 < 4; ++kk4) {
    int cb = kk4 * 64 + lg * 16;
    short8v pa = *(const short8v*)((const char*)sP + swz256(w * 16 + li, cb));
#pragma unroll
    for (int nf = 0; nf < 4; ++nf) {
      short8v vb = *(const short8v*)((const char*)sVT + swz256(nf * 16 + li, cb));
      pv[nf] = mfma16(pa, vb, pv[nf]);
    }
  }
  float* pvdst = pvP + ((size_t)bh * NCH + ch) * 4096;
#pragma unroll
  for (int nf = 0; nf < 4; ++nf)
#pragma unroll
    for (int r = 0; r < 4; ++r)
      pvdst[(w * 16 + lg * 4 + r) * 64 + nf * 16 + li] = pv[nf][r];
}

// ---------------- reduce PV partials over chunks ----------------
__global__ __launch_bounds__(256) void k_reduce(const float* __restrict__ pvP,
                                                float* __restrict__ rdraw) {
  int o = blockIdx.x * 256 + threadIdx.x;   // 1024 blocks -> 262144 = 64bh*4096
  int bh = o >> 12, qd = o & 4095;
  const float* p = pvP + (size_t)bh * NCH * 4096 + qd;
  float sm = 0.f;
#pragma unroll
  for (int ch = 0; ch < NCH; ++ch) sm += p[ch * 4096];
  rdraw[o] = sm;
}

// ---------------- middle: reph update, self-attn, xd ----------------
__global__ __launch_bounds__(256) void k_mid(const float* __restrict__ rep,
                                             const float* __restrict__ rdraw,
                                             const float* __restrict__ rsumP,
                                             const float* __restrict__ step_rep,
                                             const float* __restrict__ step_x,
                                             ushort* __restrict__ xd) {  // [bh,64,64]
  __shared__ float sSum[64];
  __shared__ float sR[64 * 65];
  __shared__ float sT[64 * 65];
  const int bh = blockIdx.x;
  const int b = bh >> 3, h = bh & 7;
  const int t = threadIdx.x;

  if (t < 64) {
    float v = 0.f;
    for (int ch = 0; ch < NCH; ++ch) v += rsumP[((size_t)bh * NCH + ch) * 64 + t];
    sSum[t] = v;
  }
  __syncthreads();
  // reph_new = rep + step_rep * (PV / rsum)
  {
    int q = t >> 2, d0 = (t & 3) * 16;
    float srep = step_rep[h];
    float inv = 1.f / sSum[q];
    const float* rp = rep + ((size_t)b * 64 + q) * CDIM + h * DH + d0;
    const float* rd = rdraw + (size_t)bh * 4096 + q * 64 + d0;
#pragma unroll
    for (int j = 0; j < 16; ++j) sR[q * 65 + d0 + j] = rp[j] + srep * (rd[j] * inv);
  }
  __syncthreads();
  // self-attn among 64 reps
  {
    int q = t >> 2, jb = (t & 3) * 16;
    float a[16];
#pragma unroll
    for (int j = 0; j < 16; ++j) {
      float accd = 0.f;
      for (int d = 0; d < 64; ++d) accd += sR[q * 65 + d] * sR[(jb + j) * 65 + d];
      a[j] = accd * SCALE;
    }
    float mx = a[0];
#pragma unroll
    for (int j = 1; j < 16; ++j) mx = fmaxf(mx, a[j]);
    mx = fmaxf(mx, __shfl_xor(mx, 1));
    mx = fmaxf(mx, __shfl_xor(mx, 2));
    float sm = 0.f;
#pragma unroll
    for (int j = 0; j < 16; ++j) { a[j] = __expf(a[j] - mx); sm += a[j]; }
    sm += __shfl_xor(sm, 1);
    sm += __shfl_xor(sm, 2);
    float inv = 1.f / sm;
#pragma unroll
    for (int j = 0; j < 16; ++j) sT[q * 65 + jb + j] = a[j] * inv;
  }
  __syncthreads();
  // xd = (step_x / rsum[q]) * (attn2 @ reph_new)
  {
    int q = t >> 2, db = (t & 3) * 16;
    float accd[16] = {};
    for (int j = 0; j < 64; ++j) {
      float w2 = sT[q * 65 + j];
#pragma unroll
      for (int d = 0; d < 16; ++d) accd[d] += w2 * sR[j * 65 + db + d];
    }
    float sc = step_x[h] / sSum[q];
    ushort o[16] __attribute__((aligned(16)));
#pragma unroll
    for (int d = 0; d < 16; ++d) o[d] = f2bf(accd[d] * sc);
    ushort* dst = xd + ((size_t)bh * 64 + q) * 64 + db;
    *(short8v*)dst = *(short8v*)&o[0];
    *(short8v*)(dst + 8) = *(short8v*)&o[8];
  }
}

// ---------------- upsample: xdt[b,n,h*64+d] = sum_q attnT[bh,n,q]*xd[bh,q,d] ----------------
__global__ __launch_bounds__(256) void k_upsample(const ushort* __restrict__ attnT,
                                                  const ushort* __restrict__ xd,
                                                  ushort* __restrict__ xdt) {
  __shared__ ushort sXT[64 * 64];   // [d][q] swizzled
  const int bh = blockIdx.y, mblk = blockIdx.x;
  const int b = bh >> 3, h = bh & 7;
  const int t = threadIdx.x, w = t >> 6, l = t & 63;
  const int lg = l >> 4, li = l & 15;
  {
    const ushort* g = xd + ((size_t)bh * 64 + l) * 64 + w * 16;
    short8v v0 = *(const short8v*)g;
    short8v v1 = *(const short8v*)(g + 8);
#pragma unroll
    for (int j = 0; j < 8; ++j) {
      *(ushort*)((char*)sXT + swz(w * 16 + j, l * 2)) = (ushort)v0[j];
      *(ushort*)((char*)sXT + swz(w * 16 + 8 + j, l * 2)) = (ushort)v1[j];
    }
  }
  __syncthreads();
  const int nbase = mblk * 256 + w * 64;
  floatx4 acc[4][4] = {};
#pragma unroll
  for (int kk = 0; kk < 2; ++kk) {
    int kb = kk * 32 + lg * 8;
    short8v bfr[4];
#pragma unroll
    for (int nf = 0; nf < 4; ++nf)
      bfr[nf] = *(const short8v*)((const char*)sXT + swz(nf * 16 + li, kb * 2));
#pragma unroll
    for (int m = 0; m < 4; ++m) {
      const ushort* ga = attnT + ((size_t)bh * NTOK + nbase + m * 16 + li) * 64 + kb;
      short8v af = *(const short8v*)ga;
#pragma unroll
      for (int nf = 0; nf < 4; ++nf) acc[m][nf] = mfma16(af, bfr[nf], acc[m][nf]);
    }
  }
#pragma unroll
  for (int m = 0; m < 4; ++m)
#pragma unroll
    for (int nf = 0; nf < 4; ++nf)
#pragma unroll
      for (int r = 0; r < 4; ++r) {
        int row = nbase + m * 16 + lg * 4 + r;
        int col = h * DH + nf * 16 + li;
        xdt[((size_t)b * NTOK + row) * CDIM + col] = f2bf(acc[m][nf][r]);
      }
}

// ---------------- launch ----------------
extern "C" void kernel_launch(void* const* d_in, const int* in_sizes, int n_in,
                              void* d_out, int out_size, void* d_ws, size_t ws_size,
                              hipStream_t stream) {
  const float* x = (const float*)d_in[0];
  const float* proj_w = (const float*)d_in[1];
  const float* step_rep = (const float*)d_in[2];
  const float* step_x = (const float*)d_in[3];
  const float* to_out_w = (const float*)d_in[4];
  const float* to_out_b = (const float*)d_in[5];
  float* out = (float*)d_out;
  char* ws = (char*)d_ws;
  char* ob = (char*)d_out;   // d_out doubles as scratch; gemm2 overwrites all of it

  // ws layout (66.5 MiB, proven available last round):
  ushort* bufA = (ushort*)(ws);                  // x_bf16  -> attnT   (32 MiB)
  ushort* bufB = (ushort*)(ws + 33554432);       // w_bf16  -> xdt     (32 MiB)
  ushort* pw   = (ushort*)(ws + 67108864);       // proj_w bf16 (512 KiB)
  ushort* tow  = (ushort*)(ws + 67633152);       // to_out_w bf16 (512 KiB)
  float*  rep  = (float*)(ws + 68157440);        // pooled rep fp32 (1 MiB)
  ushort* xd   = (ushort*)(ws + 69206016);       // xd bf16 (512 KiB)
  // d_out scratch (35.7 MiB of 64 MiB, all dead before gemm2 writes out):
  float*  pvP   = (float*)(ob);                  // PV partials (33.5 MiB)
  float*  rdraw = (float*)(ob + 33554432);       // reduced PV (1 MiB)
  ushort* qbf   = (ushort*)(ob + 34603008);      // pre-swizzled Q tiles (512 KiB)
  float*  rsumP = (float*)(ob + 35127296);       // rowsum partials (512 KiB)

  k_f2bf<<<2048, 256, 0, stream>>>(x, bufA, (Bc * NTOK * CDIM) / 4);
  k_f2bf<<<256, 256, 0, stream>>>(proj_w, pw, (CDIM * CDIM) / 4);
  k_f2bf<<<256, 256, 0, stream>>>(to_out_w, tow, (CDIM * CDIM) / 4);

  k_gemm_bt<true, false><<<dim3(CDIM / 128, (Bc * NTOK) / 128), 256, 0, stream>>>(
      bufA, pw, bufB, nullptr, Bc * NTOK, CDIM, CDIM);

  k_pool<<<Bc * 64, 256, 0, stream>>>(bufB, rep, qbf);

  k_qkexp<<<dim3(NCH, Bc * HEADS), 256, 0, stream>>>(bufB, qbf, bufA, pvP, rsumP);

  k_reduce<<<1024, 256, 0, stream>>>(pvP, rdraw);

  k_mid<<<Bc * HEADS, 256, 0, stream>>>(rep, rdraw, rsumP, step_rep, step_x, xd);

  k_upsample<<<dim3(NTOK / 256, Bc * HEADS), 256, 0, stream>>>(bufA, xd, bufB);

  k_gemm_bt<false, true><<<dim3(CDIM / 128, (Bc * NTOK) / 128), 256, 0, stream>>>(
      bufB, tow, out, to_out_b, Bc * NTOK, CDIM, CDIM);
}

// Round 3
// 142.496 us; speedup vs baseline: 1.8190x; 1.0969x over previous
//
#include <hip/hip_runtime.h>
#include <hip/hip_bf16.h>
#include <stdint.h>

// ---------------- common types / helpers ----------------
typedef __attribute__((ext_vector_type(8))) short short8v;   // 8 x bf16 (4 VGPRs)
typedef __attribute__((ext_vector_type(4))) float floatx4;

#define DEV __device__ __forceinline__

DEV ushort f2bf(float f) {                      // RNE float -> bf16 bits
  union { float f; unsigned u; } v; v.f = f;
  unsigned r = v.u + 0x7fffu + ((v.u >> 16) & 1u);
  return (ushort)(r >> 16);
}
DEV float bf2f(ushort b) {
  union { unsigned u; float f; } v; v.u = ((unsigned)b) << 16;
  return v.f;
}
// XOR swizzle for 64-col bf16 tiles (128B rows)
DEV int swz(int row, int colByte) {
  return row * 128 + (colByte ^ ((row & 7) << 4));
}
// XOR swizzle for 128-col bf16 tiles (256B rows)
DEV int swz256(int row, int colByte) {
  return row * 256 + (colByte ^ ((row & 7) << 4));
}
DEV floatx4 mfma16(short8v a, short8v b, floatx4 c) {
  return __builtin_amdgcn_mfma_f32_16x16x32_bf16(a, b, c, 0, 0, 0);
}

#define GLD_LDS16(g, l)                                                   \
  __builtin_amdgcn_global_load_lds(                                       \
      (const __attribute__((address_space(1))) void*)(g),                 \
      (__attribute__((address_space(3))) void*)(l), 16, 0, 0)

// problem constants
constexpr int Bc = 8, HEADS = 8, NTOK = 4096, CDIM = 512, DH = 64;
constexpr float SCALE = 0.125f;   // DH^-0.5
constexpr int NCH = 8, CHK = 512;    // key chunks for qkexp (4 sub-tiles of 128)

// ---------------- fp32 -> bf16 convert ----------------
__global__ void k_f2bf(const float* __restrict__ src, ushort* __restrict__ dst, int n4) {
  int i = blockIdx.x * blockDim.x + threadIdx.x;
  int stride = gridDim.x * blockDim.x;
  for (int j = i; j < n4; j += stride) {
    float4 f = ((const float4*)src)[j];
    ushort4 o;
    o.x = f2bf(f.x); o.y = f2bf(f.y); o.z = f2bf(f.z); o.w = f2bf(f.w);
    ((ushort4*)dst)[j] = o;
  }
}

// ---------------- bf16 MFMA GEMM: C[M,N] = A[M,K] @ B[N,K]^T (+bias) ----------------
template <bool OUT_BF16, bool HAS_BIAS, int NKT>
__global__ __launch_bounds__(256) void k_gemm_bt(const ushort* __restrict__ A,
                                                 const ushort* __restrict__ Bm,
                                                 void* __restrict__ Cout,
                                                 const float* __restrict__ bias,
                                                 int M, int N, int K) {
  __shared__ ushort sA[128 * 64];
  __shared__ ushort sB[128 * 64];
  const int t = threadIdx.x;
  const int w = t >> 6, l = t & 63;
  const int lg = l >> 4, li = l & 15;
  const int m0 = blockIdx.y * 128, n0 = blockIdx.x * 128;
  const int wr = (w >> 1) * 64, wc = (w & 1) * 64;
  floatx4 acc[4][4] = {};
#pragma unroll
  for (int kt = 0; kt < NKT; ++kt) {
    __syncthreads();
#pragma unroll
    for (int i = 0; i < 4; ++i) {
      int flat = i * 256 + t;
      int row = flat >> 3, pch = flat & 7;
      int sch = pch ^ (row & 7);
      const ushort* ga = A + (size_t)(m0 + row) * K + kt * 64 + sch * 8;
      GLD_LDS16(ga, (char*)sA + flat * 16);
    }
#pragma unroll
    for (int i = 0; i < 4; ++i) {
      int flat = i * 256 + t;
      int row = flat >> 3, pch = flat & 7;
      int sch = pch ^ (row & 7);
      const ushort* gb = Bm + (size_t)(n0 + row) * K + kt * 64 + sch * 8;
      GLD_LDS16(gb, (char*)sB + flat * 16);
    }
    __syncthreads();
#pragma unroll
    for (int kk = 0; kk < 2; ++kk) {
      int colb = (kk * 32 + lg * 8) * 2;
      short8v af[4], bf[4];
#pragma unroll
      for (int m = 0; m < 4; ++m) {
        int row = wr + m * 16 + li;
        af[m] = *(const short8v*)((const char*)sA + swz(row, colb));
      }
#pragma unroll
      for (int n = 0; n < 4; ++n) {
        int row = wc + n * 16 + li;
        bf[n] = *(const short8v*)((const char*)sB + swz(row, colb));
      }
#pragma unroll
      for (int m = 0; m < 4; ++m)
#pragma unroll
        for (int n = 0; n < 4; ++n)
          acc[m][n] = mfma16(af[m], bf[n], acc[m][n]);
    }
  }
#pragma unroll
  for (int m = 0; m < 4; ++m)
#pragma unroll
    for (int n = 0; n < 4; ++n) {
      int col = n0 + wc + n * 16 + li;
      float bv = HAS_BIAS ? bias[col] : 0.f;
#pragma unroll
      for (int r = 0; r < 4; ++r) {
        int row = m0 + wr + m * 16 + lg * 4 + r;
        float v = acc[m][n][r] + bv;
        if (OUT_BF16)
          ((ushort*)Cout)[(size_t)row * N + col] = f2bf(v);
        else
          ((float*)Cout)[(size_t)row * N + col] = v;
      }
    }
}

// ---------------- adaptive 8x8 pool + pre-swizzled bf16 Q tiles ----------------
__global__ __launch_bounds__(256) void k_pool(const ushort* __restrict__ wm,
                                              float* __restrict__ rep,
                                              ushort* __restrict__ qbf) {
  const int blk = blockIdx.x;      // b*64 + qi
  const int b = blk >> 6, qi = blk & 63;
  const int ph = qi >> 3, pw = qi & 7;
  const int c0 = threadIdx.x * 2;
  float a0 = 0.f, a1 = 0.f;
  for (int u = 0; u < 64; ++u) {
    int n = (ph * 8 + (u >> 3)) * 64 + pw * 8 + (u & 7);
    unsigned v = *(const unsigned*)(wm + ((size_t)b * NTOK + n) * CDIM + c0);
    a0 += bf2f((ushort)(v & 0xffff));
    a1 += bf2f((ushort)(v >> 16));
  }
  a0 *= 0.015625f; a1 *= 0.015625f;
  float* dst = rep + ((size_t)b * 64 + qi) * CDIM + c0;
  dst[0] = a0;
  dst[1] = a1;
  // bf16 Q tile, swizzled layout per (b,h): [64 q][64 d]
  int h = c0 >> 6, d0 = c0 & 63;   // d0 even
  unsigned pack = (unsigned)f2bf(a0) | ((unsigned)f2bf(a1) << 16);
  *(unsigned*)((char*)qbf + ((size_t)(b * 8 + h)) * 8192 + swz(qi, d0 * 2)) = pack;
}

// ---------------- qkexp: per (bh, chunk of 512 keys; 4 sub-tiles of 128) ----------------
// dots = Q@K^T, P = exp(dots*SCALE) (no max-sub; dots bounded ~1),
// write P^T to attnT[bh,n,q], partial rowsum -> rsumP, partial PV -> pvP.
__global__ __launch_bounds__(256) void k_qkexp(const ushort* __restrict__ wmat,
                                               const ushort* __restrict__ qbf,
                                               ushort* __restrict__ attnT,  // [bh,4096,64]
                                               float* __restrict__ pvP,     // [bh,8,64,64]
                                               float* __restrict__ rsumP) { // [bh,8,64]
  __shared__ char smem[57344] __attribute__((aligned(128)));
  ushort* sQ  = (ushort*)smem;            // [64 q][64 d]   8KB swizzled
  ushort* sK  = (ushort*)(smem + 8192);   // [128 n][64 d] 16KB swizzled
  ushort* sVT = (ushort*)(smem + 24576);  // [64 d][128 n] 16KB swizzled (256B rows)
  ushort* sP  = (ushort*)(smem + 40960);  // [64 q][128 k] 16KB swizzled (256B rows)

  const int bh = blockIdx.y, ch = blockIdx.x;
  const int b = bh >> 3, h = bh & 7;
  const int t = threadIdx.x, w = t >> 6, l = t & 63;
  const int lg = l >> 4, li = l & 15;

  // stage Q (pre-swizzled in qbf -> linear copy)
  {
    const char* qsrc = (const char*)(qbf + (size_t)bh * 4096);
#pragma unroll
    for (int i = 0; i < 2; ++i) {
      int flat = i * 256 + t;
      GLD_LDS16(qsrc + flat * 16, (char*)sQ + flat * 16);
    }
  }

  float rs[4] = {};
  floatx4 pv[4] = {};
  short8v qa[2];
  bool qaLoaded = false;

  for (int sc = 0; sc < 4; ++sc) {
    const ushort* wbase = wmat + ((size_t)b * NTOK + ch * CHK + sc * 128) * CDIM + h * DH;
    __syncthreads();   // prev sub-tile reads done (and on sc=0, nothing staged yet into K/V)
    // stage K tile (source pre-swizzled)
#pragma unroll
    for (int i = 0; i < 4; ++i) {
      int flat = i * 256 + t;
      int row = flat >> 3, pch = flat & 7;
      int sch = pch ^ (row & 7);
      GLD_LDS16(wbase + (size_t)row * CDIM + sch * 8, (char*)sK + flat * 16);
    }
    // stage V transposed: [d][n]
    {
      int n = t & 127, dh2 = (t >> 7) * 32;
      const ushort* g = wbase + (size_t)n * CDIM + dh2;
#pragma unroll
      for (int j = 0; j < 4; ++j) {
        short8v v = *(const short8v*)(g + j * 8);
#pragma unroll
        for (int e = 0; e < 8; ++e) {
          int d = dh2 + j * 8 + e;
          *(ushort*)((char*)sVT + swz256(d, 2 * n)) = (ushort)v[e];
        }
      }
    }
    __syncthreads();

    if (!qaLoaded) {   // Q A-frags (wave w owns q rows w*16..w*16+15); Q now resident
      qaLoaded = true;
#pragma unroll
      for (int kk = 0; kk < 2; ++kk)
        qa[kk] = *(const short8v*)((const char*)sQ + swz(w * 16 + li, (kk * 32 + lg * 8) * 2));
    }

    // QK^T: s[kf] = [16 q x 16 k] frag, kf over 128 keys
    floatx4 s[8] = {};
#pragma unroll
    for (int kk = 0; kk < 2; ++kk) {
      int cb = (kk * 32 + lg * 8) * 2;
#pragma unroll
      for (int kf = 0; kf < 8; ++kf) {
        short8v kb = *(const short8v*)((const char*)sK + swz(kf * 16 + li, cb));
        s[kf] = mfma16(qa[kk], kb, s[kf]);
      }
    }

    // exp, rowsum partial, attnT store, sP write
#pragma unroll
    for (int kf = 0; kf < 8; ++kf) {
      ushort pb[4];
#pragma unroll
      for (int r = 0; r < 4; ++r) {
        float p = __expf(s[kf][r] * SCALE);
        rs[r] += p;
        pb[r] = f2bf(p);
        int q = w * 16 + lg * 4 + r;
        *(ushort*)((char*)sP + swz256(q, (kf * 16 + li) * 2)) = pb[r];
      }
      int key = ch * CHK + sc * 128 + kf * 16 + li;
      ushort4 pk; pk.x = pb[0]; pk.y = pb[1]; pk.z = pb[2]; pk.w = pb[3];
      *(ushort4*)(attnT + ((size_t)bh * NTOK + key) * 64 + w * 16 + lg * 4) = pk;
    }

    // PV partial accumulate: pv[16 q x 64 d] per wave over these 128 keys.
    // sP write->read is intra-wave (same 16-row band); compiler inserts lgkmcnt.
#pragma unroll
    for (int kk4 = 0; kk4 < 4; ++kk4) {
      int cb = kk4 * 64 + lg * 16;
      short8v pa = *(const short8v*)((const char*)sP + swz256(w * 16 + li, cb));
#pragma unroll
      for (int nf = 0; nf < 4; ++nf) {
        short8v vb = *(const short8v*)((const char*)sVT + swz256(nf * 16 + li, cb));
        pv[nf] = mfma16(pa, vb, pv[nf]);
      }
    }
  }

#pragma unroll
  for (int r = 0; r < 4; ++r) {
    float v = rs[r];
    for (int mask = 1; mask < 16; mask <<= 1) v += __shfl_xor(v, mask);
    if (li == 0) rsumP[((size_t)bh * NCH + ch) * 64 + w * 16 + lg * 4 + r] = v;
  }
  float* pvdst = pvP + ((size_t)bh * NCH + ch) * 4096;
#pragma unroll
  for (int nf = 0; nf < 4; ++nf)
#pragma unroll
    for (int r = 0; r < 4; ++r)
      pvdst[(w * 16 + lg * 4 + r) * 64 + nf * 16 + li] = pv[nf][r];
}

// ---------------- middle: chunk-reduce + reph update + self-attn + xd ----------------
__global__ __launch_bounds__(256) void k_mid(const float* __restrict__ rep,
                                             const float* __restrict__ pvP,
                                             const float* __restrict__ rsumP,
                                             const float* __restrict__ step_rep,
                                             const float* __restrict__ step_x,
                                             ushort* __restrict__ xd) {  // [bh,64,64]
  __shared__ float sSum[64];
  __shared__ float sRd[4096];
  __shared__ float sR[64 * 65];
  __shared__ float sT[64 * 65];
  const int bh = blockIdx.x;
  const int b = bh >> 3, h = bh & 7;
  const int t = threadIdx.x;

  if (t < 64) {
    float v = 0.f;
#pragma unroll
    for (int ch = 0; ch < NCH; ++ch) v += rsumP[((size_t)bh * NCH + ch) * 64 + t];
    sSum[t] = v;
  }
  // reduce PV partials over chunks (coalesced)
  {
    const float* p = pvP + (size_t)bh * NCH * 4096;
#pragma unroll
    for (int j = 0; j < 16; ++j) {
      int idx = t + 256 * j;
      float sm = 0.f;
#pragma unroll
      for (int ch = 0; ch < NCH; ++ch) sm += p[ch * 4096 + idx];
      sRd[idx] = sm;
    }
  }
  __syncthreads();
  // reph_new = rep + step_rep * (PV / rsum)
  {
    int q = t >> 2, d0 = (t & 3) * 16;
    float srep = step_rep[h];
    float inv = 1.f / sSum[q];
    const float* rp = rep + ((size_t)b * 64 + q) * CDIM + h * DH + d0;
#pragma unroll
    for (int j = 0; j < 16; ++j) sR[q * 65 + d0 + j] = rp[j] + srep * (sRd[q * 64 + d0 + j] * inv);
  }
  __syncthreads();
  // self-attn among 64 reps
  {
    int q = t >> 2, jb = (t & 3) * 16;
    float a[16];
#pragma unroll
    for (int j = 0; j < 16; ++j) {
      float accd = 0.f;
      for (int d = 0; d < 64; ++d) accd += sR[q * 65 + d] * sR[(jb + j) * 65 + d];
      a[j] = accd * SCALE;
    }
    float mx = a[0];
#pragma unroll
    for (int j = 1; j < 16; ++j) mx = fmaxf(mx, a[j]);
    mx = fmaxf(mx, __shfl_xor(mx, 1));
    mx = fmaxf(mx, __shfl_xor(mx, 2));
    float sm = 0.f;
#pragma unroll
    for (int j = 0; j < 16; ++j) { a[j] = __expf(a[j] - mx); sm += a[j]; }
    sm += __shfl_xor(sm, 1);
    sm += __shfl_xor(sm, 2);
    float inv = 1.f / sm;
#pragma unroll
    for (int j = 0; j < 16; ++j) sT[q * 65 + jb + j] = a[j] * inv;
  }
  __syncthreads();
  // xd = (step_x / rsum[q]) * (attn2 @ reph_new)
  {
    int q = t >> 2, db = (t & 3) * 16;
    float accd[16] = {};
    for (int j = 0; j < 64; ++j) {
      float w2 = sT[q * 65 + j];
#pragma unroll
      for (int d = 0; d < 16; ++d) accd[d] += w2 * sR[j * 65 + db + d];
    }
    float sc = step_x[h] / sSum[q];
    ushort o[16] __attribute__((aligned(16)));
#pragma unroll
    for (int d = 0; d < 16; ++d) o[d] = f2bf(accd[d] * sc);
    ushort* dst = xd + ((size_t)bh * 64 + q) * 64 + db;
    *(short8v*)dst = *(short8v*)&o[0];
    *(short8v*)(dst + 8) = *(short8v*)&o[8];
  }
}

// ---------------- upsample: xdt[b,n,h*64+d] = sum_q attnT[bh,n,q]*xd[bh,q,d] ----------------
__global__ __launch_bounds__(256) void k_upsample(const ushort* __restrict__ attnT,
                                                  const ushort* __restrict__ xd,
                                                  ushort* __restrict__ xdt) {
  __shared__ ushort sXT[64 * 64];   // [d][q] swizzled
  const int bh = blockIdx.y, mblk = blockIdx.x;
  const int b = bh >> 3, h = bh & 7;
  const int t = threadIdx.x, w = t >> 6, l = t & 63;
  const int lg = l >> 4, li = l & 15;
  {
    const ushort* g = xd + ((size_t)bh * 64 + l) * 64 + w * 16;
    short8v v0 = *(const short8v*)g;
    short8v v1 = *(const short8v*)(g + 8);
#pragma unroll
    for (int j = 0; j < 8; ++j) {
      *(ushort*)((char*)sXT + swz(w * 16 + j, l * 2)) = (ushort)v0[j];
      *(ushort*)((char*)sXT + swz(w * 16 + 8 + j, l * 2)) = (ushort)v1[j];
    }
  }
  __syncthreads();
  const int nbase = mblk * 256 + w * 64;
  floatx4 acc[4][4] = {};
#pragma unroll
  for (int kk = 0; kk < 2; ++kk) {
    int kb = kk * 32 + lg * 8;
    short8v bfr[4];
#pragma unroll
    for (int nf = 0; nf < 4; ++nf)
      bfr[nf] = *(const short8v*)((const char*)sXT + swz(nf * 16 + li, kb * 2));
#pragma unroll
    for (int m = 0; m < 4; ++m) {
      const ushort* ga = attnT + ((size_t)bh * NTOK + nbase + m * 16 + li) * 64 + kb;
      short8v af = *(const short8v*)ga;
#pragma unroll
      for (int nf = 0; nf < 4; ++nf) acc[m][nf] = mfma16(af, bfr[nf], acc[m][nf]);
    }
  }
#pragma unroll
  for (int m = 0; m < 4; ++m)
#pragma unroll
    for (int nf = 0; nf < 4; ++nf)
#pragma unroll
      for (int r = 0; r < 4; ++r) {
        int row = nbase + m * 16 + lg * 4 + r;
        int col = h * DH + nf * 16 + li;
        xdt[((size_t)b * NTOK + row) * CDIM + col] = f2bf(acc[m][nf][r]);
      }
}

// ---------------- launch ----------------
extern "C" void kernel_launch(void* const* d_in, const int* in_sizes, int n_in,
                              void* d_out, int out_size, void* d_ws, size_t ws_size,
                              hipStream_t stream) {
  const float* x = (const float*)d_in[0];
  const float* proj_w = (const float*)d_in[1];
  const float* step_rep = (const float*)d_in[2];
  const float* step_x = (const float*)d_in[3];
  const float* to_out_w = (const float*)d_in[4];
  const float* to_out_b = (const float*)d_in[5];
  float* out = (float*)d_out;
  char* ws = (char*)d_ws;
  char* ob = (char*)d_out;   // d_out doubles as scratch; gemm2 overwrites all of it

  // ws layout:
  ushort* bufA = (ushort*)(ws);                  // x_bf16  -> attnT   (32 MiB)
  ushort* bufB = (ushort*)(ws + 33554432);       // w_bf16  -> xdt     (32 MiB)
  ushort* pw   = (ushort*)(ws + 67108864);       // proj_w bf16 (512 KiB)
  ushort* tow  = (ushort*)(ws + 67633152);       // to_out_w bf16 (512 KiB)
  float*  rep  = (float*)(ws + 68157440);        // pooled rep fp32 (1 MiB)
  ushort* xd   = (ushort*)(ws + 69206016);       // xd bf16 (512 KiB)
  // d_out scratch (all dead before gemm2 writes out):
  float*  pvP   = (float*)(ob);                  // PV partials (8.4 MiB)
  ushort* qbf   = (ushort*)(ob + 34603008);      // pre-swizzled Q tiles (512 KiB)
  float*  rsumP = (float*)(ob + 35127296);       // rowsum partials (128 KiB)

  k_f2bf<<<2048, 256, 0, stream>>>(x, bufA, (Bc * NTOK * CDIM) / 4);
  k_f2bf<<<256, 256, 0, stream>>>(proj_w, pw, (CDIM * CDIM) / 4);
  k_f2bf<<<256, 256, 0, stream>>>(to_out_w, tow, (CDIM * CDIM) / 4);

  k_gemm_bt<true, false, CDIM / 64><<<dim3(CDIM / 128, (Bc * NTOK) / 128), 256, 0, stream>>>(
      bufA, pw, bufB, nullptr, Bc * NTOK, CDIM, CDIM);

  k_pool<<<Bc * 64, 256, 0, stream>>>(bufB, rep, qbf);

  k_qkexp<<<dim3(NCH, Bc * HEADS), 256, 0, stream>>>(bufB, qbf, bufA, pvP, rsumP);

  k_mid<<<Bc * HEADS, 256, 0, stream>>>(rep, pvP, rsumP, step_rep, step_x, xd);

  k_upsample<<<dim3(NTOK / 256, Bc * HEADS), 256, 0, stream>>>(bufA, xd, bufB);

  k_gemm_bt<false, true, CDIM / 64><<<dim3(CDIM / 128, (Bc * NTOK) / 128), 256, 0, stream>>>(
      bufB, tow, out, to_out_b, Bc * NTOK, CDIM, CDIM);
}

// Round 4
// 134.688 us; speedup vs baseline: 1.9245x; 1.0580x over previous
//
#include <hip/hip_runtime.h>
#include <hip/hip_bf16.h>
#include <stdint.h>

// ---------------- common types / helpers ----------------
typedef __attribute__((ext_vector_type(8))) short short8v;   // 8 x bf16 (4 VGPRs)
typedef __attribute__((ext_vector_type(4))) float floatx4;

#define DEV __device__ __forceinline__

DEV ushort f2bf(float f) {                      // RNE float -> bf16 bits
  union { float f; unsigned u; } v; v.f = f;
  unsigned r = v.u + 0x7fffu + ((v.u >> 16) & 1u);
  return (ushort)(r >> 16);
}
DEV float bf2f(ushort b) {
  union { unsigned u; float f; } v; v.u = ((unsigned)b) << 16;
  return v.f;
}
// XOR swizzle for 64-col bf16 tiles (128B rows)
DEV int swz(int row, int colByte) {
  return row * 128 + (colByte ^ ((row & 7) << 4));
}
// XOR swizzle for 128-col bf16 tiles (256B rows)
DEV int swz256(int row, int colByte) {
  return row * 256 + (colByte ^ ((row & 7) << 4));
}
DEV floatx4 mfma16(short8v a, short8v b, floatx4 c) {
  return __builtin_amdgcn_mfma_f32_16x16x32_bf16(a, b, c, 0, 0, 0);
}

#define GLD_LDS16(g, l)                                                   \
  __builtin_amdgcn_global_load_lds(                                       \
      (const __attribute__((address_space(1))) void*)(g),                 \
      (__attribute__((address_space(3))) void*)(l), 16, 0, 0)

// problem constants
constexpr int Bc = 8, HEADS = 8, NTOK = 4096, CDIM = 512, DH = 64;
constexpr float SCALE = 0.125f;   // DH^-0.5
constexpr int NCH = 8, CHK = 512;    // key chunks for qkexp (4 sub-tiles of 128)

// ---------------- fp32 -> bf16 convert ----------------
__global__ void k_f2bf(const float* __restrict__ src, ushort* __restrict__ dst, int n4) {
  int i = blockIdx.x * blockDim.x + threadIdx.x;
  int stride = gridDim.x * blockDim.x;
  for (int j = i; j < n4; j += stride) {
    float4 f = ((const float4*)src)[j];
    ushort4 o;
    o.x = f2bf(f.x); o.y = f2bf(f.y); o.z = f2bf(f.z); o.w = f2bf(f.w);
    ((ushort4*)dst)[j] = o;
  }
}

// both weight matrices in one launch (512 blocks x 256 thr, 1 float4 each)
__global__ __launch_bounds__(256) void k_f2bfw(const float* __restrict__ a,
                                               const float* __restrict__ b,
                                               ushort* __restrict__ da,
                                               ushort* __restrict__ db) {
  int i = blockIdx.x * 256 + threadIdx.x;    // 0 .. 131071
  const float* s = (i < 65536) ? a : b;
  ushort* d = (i < 65536) ? da : db;
  int j = i & 65535;
  float4 f = ((const float4*)s)[j];
  ushort4 o;
  o.x = f2bf(f.x); o.y = f2bf(f.y); o.z = f2bf(f.z); o.w = f2bf(f.w);
  ((ushort4*)d)[j] = o;
}

// ---------------- bf16 MFMA GEMM: C[M,N] = A[M,K] @ B[N,K]^T ----------------
template <bool OUT_BF16, bool HAS_BIAS, int NKT>
__global__ __launch_bounds__(256) void k_gemm_bt(const ushort* __restrict__ A,
                                                 const ushort* __restrict__ Bm,
                                                 void* __restrict__ Cout,
                                                 const float* __restrict__ bias,
                                                 int M, int N, int K) {
  __shared__ ushort sA[128 * 64];
  __shared__ ushort sB[128 * 64];
  const int t = threadIdx.x;
  const int w = t >> 6, l = t & 63;
  const int lg = l >> 4, li = l & 15;
  const int m0 = blockIdx.y * 128, n0 = blockIdx.x * 128;
  const int wr = (w >> 1) * 64, wc = (w & 1) * 64;
  floatx4 acc[4][4] = {};
#pragma unroll
  for (int kt = 0; kt < NKT; ++kt) {
    __syncthreads();
#pragma unroll
    for (int i = 0; i < 4; ++i) {
      int flat = i * 256 + t;
      int row = flat >> 3, pch = flat & 7;
      int sch = pch ^ (row & 7);
      const ushort* ga = A + (size_t)(m0 + row) * K + kt * 64 + sch * 8;
      GLD_LDS16(ga, (char*)sA + flat * 16);
    }
#pragma unroll
    for (int i = 0; i < 4; ++i) {
      int flat = i * 256 + t;
      int row = flat >> 3, pch = flat & 7;
      int sch = pch ^ (row & 7);
      const ushort* gb = Bm + (size_t)(n0 + row) * K + kt * 64 + sch * 8;
      GLD_LDS16(gb, (char*)sB + flat * 16);
    }
    __syncthreads();
#pragma unroll
    for (int kk = 0; kk < 2; ++kk) {
      int colb = (kk * 32 + lg * 8) * 2;
      short8v af[4], bf[4];
#pragma unroll
      for (int m = 0; m < 4; ++m) {
        int row = wr + m * 16 + li;
        af[m] = *(const short8v*)((const char*)sA + swz(row, colb));
      }
#pragma unroll
      for (int n = 0; n < 4; ++n) {
        int row = wc + n * 16 + li;
        bf[n] = *(const short8v*)((const char*)sB + swz(row, colb));
      }
#pragma unroll
      for (int m = 0; m < 4; ++m)
#pragma unroll
        for (int n = 0; n < 4; ++n)
          acc[m][n] = mfma16(af[m], bf[n], acc[m][n]);
    }
  }
#pragma unroll
  for (int m = 0; m < 4; ++m)
#pragma unroll
    for (int n = 0; n < 4; ++n) {
      int col = n0 + wc + n * 16 + li;
      float bv = HAS_BIAS ? bias[col] : 0.f;
#pragma unroll
      for (int r = 0; r < 4; ++r) {
        int row = m0 + wr + m * 16 + lg * 4 + r;
        float v = acc[m][n][r] + bv;
        if (OUT_BF16)
          ((ushort*)Cout)[(size_t)row * N + col] = f2bf(v);
        else
          ((float*)Cout)[(size_t)row * N + col] = v;
      }
    }
}

// ---------------- final batched GEMM: out[b,n,d] = sum_hq attnT[b,h,n,q]*M2T[b,d,hq] + bias ----------------
// K-tile kt == head h; A rows are 128B contiguous within an h-slab.
__global__ __launch_bounds__(256) void k_gemm3(const ushort* __restrict__ attnT, // [b,8,4096,64]
                                               const ushort* __restrict__ M2T,   // [b,512,512]
                                               float* __restrict__ out,          // [b,4096,512]
                                               const float* __restrict__ bias) {
  __shared__ ushort sA[128 * 64];
  __shared__ ushort sB[128 * 64];
  const int t = threadIdx.x;
  const int w = t >> 6, l = t & 63;
  const int lg = l >> 4, li = l & 15;
  const int b = blockIdx.z;
  const int m0 = blockIdx.y * 128, n0 = blockIdx.x * 128;
  const int wr = (w >> 1) * 64, wc = (w & 1) * 64;
  const ushort* Bb = M2T + (size_t)b * 262144;
  floatx4 acc[4][4] = {};
#pragma unroll
  for (int kt = 0; kt < 8; ++kt) {
    __syncthreads();
#pragma unroll
    for (int i = 0; i < 4; ++i) {
      int flat = i * 256 + t;
      int row = flat >> 3, pch = flat & 7;
      int sch = pch ^ (row & 7);
      const ushort* ga = attnT + (((size_t)(b * 8 + kt)) * NTOK + m0 + row) * 64 + sch * 8;
      GLD_LDS16(ga, (char*)sA + flat * 16);
    }
#pragma unroll
    for (int i = 0; i < 4; ++i) {
      int flat = i * 256 + t;
      int row = flat >> 3, pch = flat & 7;
      int sch = pch ^ (row & 7);
      const ushort* gb = Bb + (size_t)(n0 + row) * 512 + kt * 64 + sch * 8;
      GLD_LDS16(gb, (char*)sB + flat * 16);
    }
    __syncthreads();
#pragma unroll
    for (int kk = 0; kk < 2; ++kk) {
      int colb = (kk * 32 + lg * 8) * 2;
      short8v af[4], bf[4];
#pragma unroll
      for (int m = 0; m < 4; ++m)
        af[m] = *(const short8v*)((const char*)sA + swz(wr + m * 16 + li, colb));
#pragma unroll
      for (int n = 0; n < 4; ++n)
        bf[n] = *(const short8v*)((const char*)sB + swz(wc + n * 16 + li, colb));
#pragma unroll
      for (int m = 0; m < 4; ++m)
#pragma unroll
        for (int n = 0; n < 4; ++n)
          acc[m][n] = mfma16(af[m], bf[n], acc[m][n]);
    }
  }
#pragma unroll
  for (int m = 0; m < 4; ++m)
#pragma unroll
    for (int n = 0; n < 4; ++n) {
      int col = n0 + wc + n * 16 + li;
      float bv = bias[col];
#pragma unroll
      for (int r = 0; r < 4; ++r) {
        int row = m0 + wr + m * 16 + lg * 4 + r;
        out[((size_t)b * NTOK + row) * CDIM + col] = acc[m][n][r] + bv;
      }
    }
}

// ---------------- adaptive 8x8 pool + pre-swizzled bf16 Q tiles ----------------
__global__ __launch_bounds__(256) void k_pool(const ushort* __restrict__ wm,
                                              float* __restrict__ rep,
                                              ushort* __restrict__ qbf) {
  const int blk = blockIdx.x;      // b*64 + qi
  const int b = blk >> 6, qi = blk & 63;
  const int ph = qi >> 3, pw = qi & 7;
  const int c0 = threadIdx.x * 2;
  float a0 = 0.f, a1 = 0.f;
  for (int u = 0; u < 64; ++u) {
    int n = (ph * 8 + (u >> 3)) * 64 + pw * 8 + (u & 7);
    unsigned v = *(const unsigned*)(wm + ((size_t)b * NTOK + n) * CDIM + c0);
    a0 += bf2f((ushort)(v & 0xffff));
    a1 += bf2f((ushort)(v >> 16));
  }
  a0 *= 0.015625f; a1 *= 0.015625f;
  float* dst = rep + ((size_t)b * 64 + qi) * CDIM + c0;
  dst[0] = a0;
  dst[1] = a1;
  // bf16 Q tile, swizzled layout per (b,h): [64 q][64 d]
  int h = c0 >> 6, d0 = c0 & 63;   // d0 even
  unsigned pack = (unsigned)f2bf(a0) | ((unsigned)f2bf(a1) << 16);
  *(unsigned*)((char*)qbf + ((size_t)(b * 8 + h)) * 8192 + swz(qi, d0 * 2)) = pack;
}

// ---------------- qkexp: per (bh, chunk of 512 keys; 4 sub-tiles of 128) ----------------
__global__ __launch_bounds__(256) void k_qkexp(const ushort* __restrict__ wmat,
                                               const ushort* __restrict__ qbf,
                                               ushort* __restrict__ attnT,  // [bh,4096,64]
                                               float* __restrict__ pvP,     // [bh,8,64,64]
                                               float* __restrict__ rsumP) { // [bh,8,64]
  __shared__ char smem[57344] __attribute__((aligned(128)));
  ushort* sQ  = (ushort*)smem;            // [64 q][64 d]   8KB swizzled
  ushort* sK  = (ushort*)(smem + 8192);   // [128 n][64 d] 16KB swizzled
  ushort* sVT = (ushort*)(smem + 24576);  // [64 d][128 n] 16KB swizzled (256B rows)
  ushort* sP  = (ushort*)(smem + 40960);  // [64 q][128 k] 16KB swizzled (256B rows)

  const int bh = blockIdx.y, ch = blockIdx.x;
  const int b = bh >> 3, h = bh & 7;
  const int t = threadIdx.x, w = t >> 6, l = t & 63;
  const int lg = l >> 4, li = l & 15;

  // stage Q (pre-swizzled in qbf -> linear copy)
  {
    const char* qsrc = (const char*)(qbf + (size_t)bh * 4096);
#pragma unroll
    for (int i = 0; i < 2; ++i) {
      int flat = i * 256 + t;
      GLD_LDS16(qsrc + flat * 16, (char*)sQ + flat * 16);
    }
  }

  float rs[4] = {};
  floatx4 pv[4] = {};
  short8v qa[2];
  bool qaLoaded = false;

  for (int sc = 0; sc < 4; ++sc) {
    const ushort* wbase = wmat + ((size_t)b * NTOK + ch * CHK + sc * 128) * CDIM + h * DH;
    __syncthreads();
    // stage K tile (source pre-swizzled)
#pragma unroll
    for (int i = 0; i < 4; ++i) {
      int flat = i * 256 + t;
      int row = flat >> 3, pch = flat & 7;
      int sch = pch ^ (row & 7);
      GLD_LDS16(wbase + (size_t)row * CDIM + sch * 8, (char*)sK + flat * 16);
    }
    // stage V transposed: [d][n]
    {
      int n = t & 127, dh2 = (t >> 7) * 32;
      const ushort* g = wbase + (size_t)n * CDIM + dh2;
#pragma unroll
      for (int j = 0; j < 4; ++j) {
        short8v v = *(const short8v*)(g + j * 8);
#pragma unroll
        for (int e = 0; e < 8; ++e) {
          int d = dh2 + j * 8 + e;
          *(ushort*)((char*)sVT + swz256(d, 2 * n)) = (ushort)v[e];
        }
      }
    }
    __syncthreads();

    if (!qaLoaded) {
      qaLoaded = true;
#pragma unroll
      for (int kk = 0; kk < 2; ++kk)
        qa[kk] = *(const short8v*)((const char*)sQ + swz(w * 16 + li, (kk * 32 + lg * 8) * 2));
    }

    // QK^T
    floatx4 s[8] = {};
#pragma unroll
    for (int kk = 0; kk < 2; ++kk) {
      int cb = (kk * 32 + lg * 8) * 2;
#pragma unroll
      for (int kf = 0; kf < 8; ++kf) {
        short8v kb = *(const short8v*)((const char*)sK + swz(kf * 16 + li, cb));
        s[kf] = mfma16(qa[kk], kb, s[kf]);
      }
    }

    // exp, rowsum partial, attnT store, sP write
#pragma unroll
    for (int kf = 0; kf < 8; ++kf) {
      ushort pb[4];
#pragma unroll
      for (int r = 0; r < 4; ++r) {
        float p = __expf(s[kf][r] * SCALE);
        rs[r] += p;
        pb[r] = f2bf(p);
        int q = w * 16 + lg * 4 + r;
        *(ushort*)((char*)sP + swz256(q, (kf * 16 + li) * 2)) = pb[r];
      }
      int key = ch * CHK + sc * 128 + kf * 16 + li;
      ushort4 pk; pk.x = pb[0]; pk.y = pb[1]; pk.z = pb[2]; pk.w = pb[3];
      *(ushort4*)(attnT + ((size_t)bh * NTOK + key) * 64 + w * 16 + lg * 4) = pk;
    }

    // PV partial accumulate over these 128 keys
#pragma unroll
    for (int kk4 = 0; kk4 < 4; ++kk4) {
      int cb = kk4 * 64 + lg * 16;
      short8v pa = *(const short8v*)((const char*)sP + swz256(w * 16 + li, cb));
#pragma unroll
      for (int nf = 0; nf < 4; ++nf) {
        short8v vb = *(const short8v*)((const char*)sVT + swz256(nf * 16 + li, cb));
        pv[nf] = mfma16(pa, vb, pv[nf]);
      }
    }
  }

#pragma unroll
  for (int r = 0; r < 4; ++r) {
    float v = rs[r];
    for (int mask = 1; mask < 16; mask <<= 1) v += __shfl_xor(v, mask);
    if (li == 0) rsumP[((size_t)bh * NCH + ch) * 64 + w * 16 + lg * 4 + r] = v;
  }
  float* pvdst = pvP + ((size_t)bh * NCH + ch) * 4096;
#pragma unroll
  for (int nf = 0; nf < 4; ++nf)
#pragma unroll
    for (int r = 0; r < 4; ++r)
      pvdst[(w * 16 + lg * 4 + r) * 64 + nf * 16 + li] = pv[nf][r];
}

// ---------------- middle: chunk-reduce + reph update + self-attn + xd ----------------
__global__ __launch_bounds__(256) void k_mid(const float* __restrict__ rep,
                                             const float* __restrict__ pvP,
                                             const float* __restrict__ rsumP,
                                             const float* __restrict__ step_rep,
                                             const float* __restrict__ step_x,
                                             ushort* __restrict__ xd) {  // [bh,64,64]
  __shared__ float sSum[64];
  __shared__ float sRd[4096];
  __shared__ float sR[64 * 65];
  __shared__ float sT[64 * 65];
  const int bh = blockIdx.x;
  const int b = bh >> 3, h = bh & 7;
  const int t = threadIdx.x;

  if (t < 64) {
    float v = 0.f;
#pragma unroll
    for (int ch = 0; ch < NCH; ++ch) v += rsumP[((size_t)bh * NCH + ch) * 64 + t];
    sSum[t] = v;
  }
  {
    const float* p = pvP + (size_t)bh * NCH * 4096;
#pragma unroll
    for (int j = 0; j < 16; ++j) {
      int idx = t + 256 * j;
      float sm = 0.f;
#pragma unroll
      for (int ch = 0; ch < NCH; ++ch) sm += p[ch * 4096 + idx];
      sRd[idx] = sm;
    }
  }
  __syncthreads();
  {
    int q = t >> 2, d0 = (t & 3) * 16;
    float srep = step_rep[h];
    float inv = 1.f / sSum[q];
    const float* rp = rep + ((size_t)b * 64 + q) * CDIM + h * DH + d0;
#pragma unroll
    for (int j = 0; j < 16; ++j) sR[q * 65 + d0 + j] = rp[j] + srep * (sRd[q * 64 + d0 + j] * inv);
  }
  __syncthreads();
  {
    int q = t >> 2, jb = (t & 3) * 16;
    float a[16];
#pragma unroll
    for (int j = 0; j < 16; ++j) {
      float accd = 0.f;
      for (int d = 0; d < 64; ++d) accd += sR[q * 65 + d] * sR[(jb + j) * 65 + d];
      a[j] = accd * SCALE;
    }
    float mx = a[0];
#pragma unroll
    for (int j = 1; j < 16; ++j) mx = fmaxf(mx, a[j]);
    mx = fmaxf(mx, __shfl_xor(mx, 1));
    mx = fmaxf(mx, __shfl_xor(mx, 2));
    float sm = 0.f;
#pragma unroll
    for (int j = 0; j < 16; ++j) { a[j] = __expf(a[j] - mx); sm += a[j]; }
    sm += __shfl_xor(sm, 1);
    sm += __shfl_xor(sm, 2);
    float inv = 1.f / sm;
#pragma unroll
    for (int j = 0; j < 16; ++j) sT[q * 65 + jb + j] = a[j] * inv;
  }
  __syncthreads();
  {
    int q = t >> 2, db = (t & 3) * 16;
    float accd[16] = {};
    for (int j = 0; j < 64; ++j) {
      float w2 = sT[q * 65 + j];
#pragma unroll
      for (int d = 0; d < 16; ++d) accd[d] += w2 * sR[j * 65 + db + d];
    }
    float sc = step_x[h] / sSum[q];
    ushort o[16] __attribute__((aligned(16)));
#pragma unroll
    for (int d = 0; d < 16; ++d) o[d] = f2bf(accd[d] * sc);
    ushort* dst = xd + ((size_t)bh * 64 + q) * 64 + db;
    *(short8v*)dst = *(short8v*)&o[0];
    *(short8v*)(dst + 8) = *(short8v*)&o[8];
  }
}

// ---------------- m2: M2T[b,d,h*64+q] = sum_dd xd[bh,q,dd] * tow[d,h*64+dd] ----------------
// one block per (b,h); wave w covers d rows [w*128,(w+1)*128); operands direct from L2.
__global__ __launch_bounds__(256) void k_m2(const ushort* __restrict__ xd,
                                            const ushort* __restrict__ tow,
                                            ushort* __restrict__ m2t) {
  const int bh = blockIdx.x;
  const int b = bh >> 3, h = bh & 7;
  const int t = threadIdx.x, w = t >> 6, l = t & 63;
  const int lg = l >> 4, li = l & 15;
  floatx4 acc[8][4] = {};
#pragma unroll
  for (int kk = 0; kk < 2; ++kk) {
    int dd0 = kk * 32 + lg * 8;
    short8v bf[4];
#pragma unroll
    for (int nf = 0; nf < 4; ++nf)
      bf[nf] = *(const short8v*)(xd + ((size_t)bh * 64 + nf * 16 + li) * 64 + dd0);
#pragma unroll
    for (int m = 0; m < 8; ++m) {
      int d = w * 128 + m * 16 + li;
      short8v af = *(const short8v*)(tow + (size_t)d * CDIM + h * DH + dd0);
#pragma unroll
      for (int nf = 0; nf < 4; ++nf) acc[m][nf] = mfma16(af, bf[nf], acc[m][nf]);
    }
  }
#pragma unroll
  for (int m = 0; m < 8; ++m)
#pragma unroll
    for (int nf = 0; nf < 4; ++nf)
#pragma unroll
      for (int r = 0; r < 4; ++r) {
        int d = w * 128 + m * 16 + lg * 4 + r;
        int hq = h * 64 + nf * 16 + li;
        m2t[((size_t)b * CDIM + d) * CDIM + hq] = f2bf(acc[m][nf][r]);
      }
}

// ---------------- launch ----------------
extern "C" void kernel_launch(void* const* d_in, const int* in_sizes, int n_in,
                              void* d_out, int out_size, void* d_ws, size_t ws_size,
                              hipStream_t stream) {
  const float* x = (const float*)d_in[0];
  const float* proj_w = (const float*)d_in[1];
  const float* step_rep = (const float*)d_in[2];
  const float* step_x = (const float*)d_in[3];
  const float* to_out_w = (const float*)d_in[4];
  const float* to_out_b = (const float*)d_in[5];
  float* out = (float*)d_out;
  char* ws = (char*)d_ws;
  char* ob = (char*)d_out;   // d_out doubles as scratch until gemm3 overwrites it

  // ws layout:
  ushort* bufA = (ushort*)(ws);                  // x_bf16  -> attnT        (32 MiB)
  ushort* bufB = (ushort*)(ws + 33554432);       // w bf16  -> M2T overlay  (32 MiB)
  ushort* pw   = (ushort*)(ws + 67108864);       // proj_w bf16 (512 KiB)
  ushort* tow  = (ushort*)(ws + 67633152);       // to_out_w bf16 (512 KiB)
  float*  rep  = (float*)(ws + 68157440);        // pooled rep fp32 (1 MiB)
  ushort* xd   = (ushort*)(ws + 69206016);       // xd bf16 (512 KiB)
  // d_out scratch (all dead before gemm3 writes out):
  float*  pvP   = (float*)(ob);                  // PV partials (8.4 MiB)
  ushort* qbf   = (ushort*)(ob + 34603008);      // pre-swizzled Q tiles (512 KiB)
  float*  rsumP = (float*)(ob + 35127296);       // rowsum partials (128 KiB)
  ushort* m2t   = bufB;                          // M2T overlays w after qkexp

  k_f2bf<<<2048, 256, 0, stream>>>(x, bufA, (Bc * NTOK * CDIM) / 4);
  k_f2bfw<<<512, 256, 0, stream>>>(proj_w, to_out_w, pw, tow);

  k_gemm_bt<true, false, CDIM / 64><<<dim3(CDIM / 128, (Bc * NTOK) / 128), 256, 0, stream>>>(
      bufA, pw, bufB, nullptr, Bc * NTOK, CDIM, CDIM);

  k_pool<<<Bc * 64, 256, 0, stream>>>(bufB, rep, qbf);

  k_qkexp<<<dim3(NCH, Bc * HEADS), 256, 0, stream>>>(bufB, qbf, bufA, pvP, rsumP);

  k_mid<<<Bc * HEADS, 256, 0, stream>>>(rep, pvP, rsumP, step_rep, step_x, xd);

  k_m2<<<Bc * HEADS, 256, 0, stream>>>(xd, tow, m2t);

  k_gemm3<<<dim3(CDIM / 128, NTOK / 128, Bc), 256, 0, stream>>>(bufA, m2t, out, to_out_b);
}

// Round 5
// 114.731 us; speedup vs baseline: 2.2592x; 1.1739x over previous
//
#include <hip/hip_runtime.h>
#include <hip/hip_bf16.h>
#include <stdint.h>

// ---------------- common types / helpers ----------------
typedef __attribute__((ext_vector_type(8))) short short8v;   // 8 x bf16 (4 VGPRs)
typedef __attribute__((ext_vector_type(4))) float floatx4;
typedef __attribute__((ext_vector_type(4))) unsigned uintx4;

#define DEV __device__ __forceinline__

DEV ushort f2bf(float f) {                      // RNE float -> bf16 bits
  union { float f; unsigned u; } v; v.f = f;
  unsigned r = v.u + 0x7fffu + ((v.u >> 16) & 1u);
  return (ushort)(r >> 16);
}
DEV float bf2f(ushort b) {
  union { unsigned u; float f; } v; v.u = ((unsigned)b) << 16;
  return v.f;
}
DEV unsigned cvtpk(float lo, float hi) {        // packed f32->bf16 (RNE), 1 inst
  unsigned r;
  asm("v_cvt_pk_bf16_f32 %0, %1, %2" : "=v"(r) : "v"(lo), "v"(hi));
  return r;
}
// XOR swizzle for 64-col bf16 tiles (128B rows)
DEV int swz(int row, int colByte) {
  return row * 128 + (colByte ^ ((row & 7) << 4));
}
// XOR swizzle for 128-col bf16 tiles (256B rows)
DEV int swz256(int row, int colByte) {
  return row * 256 + (colByte ^ ((row & 7) << 4));
}
DEV floatx4 mfma16(short8v a, short8v b, floatx4 c) {
  return __builtin_amdgcn_mfma_f32_16x16x32_bf16(a, b, c, 0, 0, 0);
}

#define GLD_LDS16(g, l)                                                   \
  __builtin_amdgcn_global_load_lds(                                       \
      (const __attribute__((address_space(1))) void*)(g),                 \
      (__attribute__((address_space(3))) void*)(l), 16, 0, 0)

// problem constants
constexpr int Bc = 8, HEADS = 8, NTOK = 4096, CDIM = 512, DH = 64;
constexpr float SCALE = 0.125f;   // DH^-0.5
constexpr int NCH = 8, CHK = 512;    // key chunks for qkexp (4 sub-tiles of 128)

// both weight matrices in one launch (512 blocks x 256 thr, 1 float4 each)
__global__ __launch_bounds__(256) void k_f2bfw(const float* __restrict__ a,
                                               const float* __restrict__ b,
                                               ushort* __restrict__ da,
                                               ushort* __restrict__ db) {
  int i = blockIdx.x * 256 + threadIdx.x;    // 0 .. 131071
  const float* s = (i < 65536) ? a : b;
  ushort* d = (i < 65536) ? da : db;
  int j = i & 65535;
  float4 f = ((const float4*)s)[j];
  ushort4 o;
  o.x = f2bf(f.x); o.y = f2bf(f.y); o.z = f2bf(f.z); o.w = f2bf(f.w);
  ((ushort4*)d)[j] = o;
}

// ---------------- gemm1 fused: w[M,N] = bf16(x[M,K]) @ pw[N,K]^T, bf16 out ----------------
// A is fp32 in global; staged via reg + v_cvt_pk_bf16_f32 + swizzled ds_write_b128.
// XCD-chunked block swizzle: xcd = bid%8 owns 128 consecutive flat tiles.
__global__ __launch_bounds__(256) void k_gemm1f(const float* __restrict__ A,
                                                const ushort* __restrict__ Bm,
                                                ushort* __restrict__ Cout) {
  __shared__ ushort sA[128 * 64];
  __shared__ ushort sB[128 * 64];
  const int t = threadIdx.x;
  const int w = t >> 6, l = t & 63;
  const int lg = l >> 4, li = l & 15;
  const int bid = blockIdx.x;                  // 1024 blocks
  const int f = (bid & 7) * 128 + (bid >> 3);  // bijective XCD chunking
  const int m0 = (f >> 2) * 128, n0 = (f & 3) * 128;
  const int wr = (w >> 1) * 64, wc = (w & 1) * 64;
  const int K = CDIM;
  floatx4 acc[4][4] = {};
#pragma unroll
  for (int kt = 0; kt < 8; ++kt) {
    // A fp32 -> regs (no LDS hazard; issue before barrier)
    float4 fa[4][2];
#pragma unroll
    for (int i = 0; i < 4; ++i) {
      int flat = i * 256 + t;
      int row = flat >> 3, pch = flat & 7;
      const float* ga = A + (size_t)(m0 + row) * K + kt * 64 + pch * 8;
      fa[i][0] = *(const float4*)ga;
      fa[i][1] = *(const float4*)(ga + 4);
    }
    __syncthreads();   // prior LDS reads done
    // B staging (source pre-swizzled, linear LDS dest)
#pragma unroll
    for (int i = 0; i < 4; ++i) {
      int flat = i * 256 + t;
      int row = flat >> 3, pch = flat & 7;
      int sch = pch ^ (row & 7);
      const ushort* gb = Bm + (size_t)(n0 + row) * K + kt * 64 + sch * 8;
      GLD_LDS16(gb, (char*)sB + flat * 16);
    }
    // A convert + swizzled ds_write_b128
#pragma unroll
    for (int i = 0; i < 4; ++i) {
      int flat = i * 256 + t;
      int row = flat >> 3, pch = flat & 7;
      uintx4 pk;
      pk.x = cvtpk(fa[i][0].x, fa[i][0].y);
      pk.y = cvtpk(fa[i][0].z, fa[i][0].w);
      pk.z = cvtpk(fa[i][1].x, fa[i][1].y);
      pk.w = cvtpk(fa[i][1].z, fa[i][1].w);
      *(uintx4*)((char*)sA + row * 128 + ((pch ^ (row & 7)) << 4)) = pk;
    }
    __syncthreads();
#pragma unroll
    for (int kk = 0; kk < 2; ++kk) {
      int colb = (kk * 32 + lg * 8) * 2;
      short8v af[4], bf[4];
#pragma unroll
      for (int m = 0; m < 4; ++m)
        af[m] = *(const short8v*)((const char*)sA + swz(wr + m * 16 + li, colb));
#pragma unroll
      for (int n = 0; n < 4; ++n)
        bf[n] = *(const short8v*)((const char*)sB + swz(wc + n * 16 + li, colb));
#pragma unroll
      for (int m = 0; m < 4; ++m)
#pragma unroll
        for (int n = 0; n < 4; ++n)
          acc[m][n] = mfma16(af[m], bf[n], acc[m][n]);
    }
  }
#pragma unroll
  for (int m = 0; m < 4; ++m)
#pragma unroll
    for (int n = 0; n < 4; ++n) {
      int col = n0 + wc + n * 16 + li;
#pragma unroll
      for (int r = 0; r < 4; ++r) {
        int row = m0 + wr + m * 16 + lg * 4 + r;
        Cout[(size_t)row * CDIM + col] = f2bf(acc[m][n][r]);
      }
    }
}

// ---------------- final batched GEMM: out[b,n,d] = sum_hq attnT[b,h,n,q]*M2T[b,d,hq] + bias ----------------
// XCD chunking: xcd == b, so each XCD's 4 MiB attnT slab lives in its own L2.
__global__ __launch_bounds__(256) void k_gemm3(const ushort* __restrict__ attnT, // [b,8,4096,64]
                                               const ushort* __restrict__ M2T,   // [b,512,512]
                                               float* __restrict__ out,          // [b,4096,512]
                                               const float* __restrict__ bias) {
  __shared__ ushort sA[128 * 64];
  __shared__ ushort sB[128 * 64];
  const int t = threadIdx.x;
  const int w = t >> 6, l = t & 63;
  const int lg = l >> 4, li = l & 15;
  const int bid = blockIdx.x;          // 1024
  const int b = bid & 7;               // one batch per XCD
  const int idx = bid >> 3;            // 0..127
  const int m0 = (idx >> 2) * 128, n0 = (idx & 3) * 128;
  const int wr = (w >> 1) * 64, wc = (w & 1) * 64;
  const ushort* Bb = M2T + (size_t)b * 262144;
  floatx4 acc[4][4] = {};
#pragma unroll
  for (int kt = 0; kt < 8; ++kt) {
    __syncthreads();
#pragma unroll
    for (int i = 0; i < 4; ++i) {
      int flat = i * 256 + t;
      int row = flat >> 3, pch = flat & 7;
      int sch = pch ^ (row & 7);
      const ushort* ga = attnT + (((size_t)(b * 8 + kt)) * NTOK + m0 + row) * 64 + sch * 8;
      GLD_LDS16(ga, (char*)sA + flat * 16);
    }
#pragma unroll
    for (int i = 0; i < 4; ++i) {
      int flat = i * 256 + t;
      int row = flat >> 3, pch = flat & 7;
      int sch = pch ^ (row & 7);
      const ushort* gb = Bb + (size_t)(n0 + row) * 512 + kt * 64 + sch * 8;
      GLD_LDS16(gb, (char*)sB + flat * 16);
    }
    __syncthreads();
#pragma unroll
    for (int kk = 0; kk < 2; ++kk) {
      int colb = (kk * 32 + lg * 8) * 2;
      short8v af[4], bf[4];
#pragma unroll
      for (int m = 0; m < 4; ++m)
        af[m] = *(const short8v*)((const char*)sA + swz(wr + m * 16 + li, colb));
#pragma unroll
      for (int n = 0; n < 4; ++n)
        bf[n] = *(const short8v*)((const char*)sB + swz(wc + n * 16 + li, colb));
#pragma unroll
      for (int m = 0; m < 4; ++m)
#pragma unroll
        for (int n = 0; n < 4; ++n)
          acc[m][n] = mfma16(af[m], bf[n], acc[m][n]);
    }
  }
#pragma unroll
  for (int m = 0; m < 4; ++m)
#pragma unroll
    for (int n = 0; n < 4; ++n) {
      int col = n0 + wc + n * 16 + li;
      float bv = bias[col];
#pragma unroll
      for (int r = 0; r < 4; ++r) {
        int row = m0 + wr + m * 16 + lg * 4 + r;
        out[((size_t)b * NTOK + row) * CDIM + col] = acc[m][n][r] + bv;
      }
    }
}

// ---------------- adaptive 8x8 pool + pre-swizzled bf16 Q tiles ----------------
__global__ __launch_bounds__(256) void k_pool(const ushort* __restrict__ wm,
                                              float* __restrict__ rep,
                                              ushort* __restrict__ qbf) {
  const int blk = blockIdx.x;      // b*64 + qi
  const int b = blk >> 6, qi = blk & 63;
  const int ph = qi >> 3, pw = qi & 7;
  const int c0 = threadIdx.x * 2;
  float a0 = 0.f, a1 = 0.f;
  for (int u = 0; u < 64; ++u) {
    int n = (ph * 8 + (u >> 3)) * 64 + pw * 8 + (u & 7);
    unsigned v = *(const unsigned*)(wm + ((size_t)b * NTOK + n) * CDIM + c0);
    a0 += bf2f((ushort)(v & 0xffff));
    a1 += bf2f((ushort)(v >> 16));
  }
  a0 *= 0.015625f; a1 *= 0.015625f;
  float* dst = rep + ((size_t)b * 64 + qi) * CDIM + c0;
  dst[0] = a0;
  dst[1] = a1;
  // bf16 Q tile, swizzled layout per (b,h): [64 q][64 d]
  int h = c0 >> 6, d0 = c0 & 63;   // d0 even
  unsigned pack = (unsigned)f2bf(a0) | ((unsigned)f2bf(a1) << 16);
  *(unsigned*)((char*)qbf + ((size_t)(b * 8 + h)) * 8192 + swz(qi, d0 * 2)) = pack;
}

// ---------------- qkexp: per (bh, chunk of 512 keys; 4 sub-tiles of 128) ----------------
__global__ __launch_bounds__(256) void k_qkexp(const ushort* __restrict__ wmat,
                                               const ushort* __restrict__ qbf,
                                               ushort* __restrict__ attnT,  // [bh,4096,64]
                                               float* __restrict__ pvP,     // [bh,8,64,64]
                                               float* __restrict__ rsumP) { // [bh,8,64]
  __shared__ char smem[57344] __attribute__((aligned(128)));
  ushort* sQ  = (ushort*)smem;            // [64 q][64 d]   8KB swizzled
  ushort* sK  = (ushort*)(smem + 8192);   // [128 n][64 d] 16KB swizzled
  ushort* sVT = (ushort*)(smem + 24576);  // [64 d][128 n] 16KB swizzled (256B rows)
  ushort* sP  = (ushort*)(smem + 40960);  // [64 q][128 k] 16KB swizzled (256B rows)

  const int bh = blockIdx.y, ch = blockIdx.x;
  const int b = bh >> 3, h = bh & 7;
  const int t = threadIdx.x, w = t >> 6, l = t & 63;
  const int lg = l >> 4, li = l & 15;

  // stage Q (pre-swizzled in qbf -> linear copy)
  {
    const char* qsrc = (const char*)(qbf + (size_t)bh * 4096);
#pragma unroll
    for (int i = 0; i < 2; ++i) {
      int flat = i * 256 + t;
      GLD_LDS16(qsrc + flat * 16, (char*)sQ + flat * 16);
    }
  }

  float rs[4] = {};
  floatx4 pv[4] = {};
  short8v qa[2];
  bool qaLoaded = false;

  for (int sc = 0; sc < 4; ++sc) {
    const ushort* wbase = wmat + ((size_t)b * NTOK + ch * CHK + sc * 128) * CDIM + h * DH;
    __syncthreads();
    // stage K tile (source pre-swizzled)
#pragma unroll
    for (int i = 0; i < 4; ++i) {
      int flat = i * 256 + t;
      int row = flat >> 3, pch = flat & 7;
      int sch = pch ^ (row & 7);
      GLD_LDS16(wbase + (size_t)row * CDIM + sch * 8, (char*)sK + flat * 16);
    }
    // stage V transposed: [d][n] — each thread owns an n-pair x 16 d's,
    // packs two columns into u32 ds_write_b32 (4x fewer DS ops than u16)
    {
      int u = t & 63;                 // n-pair: columns 2u, 2u+1
      int dh2 = (t >> 6) * 16;        // 16 d's
      const ushort* g0 = wbase + (size_t)(2 * u) * CDIM + dh2;
      const ushort* g1 = g0 + CDIM;
      short8v a0 = *(const short8v*)g0;
      short8v a1 = *(const short8v*)(g0 + 8);
      short8v b0 = *(const short8v*)g1;
      short8v b1 = *(const short8v*)(g1 + 8);
#pragma unroll
      for (int j = 0; j < 8; ++j) {
        unsigned w0 = ((unsigned)(ushort)a0[j]) | (((unsigned)(ushort)b0[j]) << 16);
        *(unsigned*)((char*)sVT + swz256(dh2 + j, 4 * u)) = w0;
        unsigned w1 = ((unsigned)(ushort)a1[j]) | (((unsigned)(ushort)b1[j]) << 16);
        *(unsigned*)((char*)sVT + swz256(dh2 + 8 + j, 4 * u)) = w1;
      }
    }
    __syncthreads();

    if (!qaLoaded) {
      qaLoaded = true;
#pragma unroll
      for (int kk = 0; kk < 2; ++kk)
        qa[kk] = *(const short8v*)((const char*)sQ + swz(w * 16 + li, (kk * 32 + lg * 8) * 2));
    }

    // QK^T
    floatx4 s[8] = {};
#pragma unroll
    for (int kk = 0; kk < 2; ++kk) {
      int cb = (kk * 32 + lg * 8) * 2;
#pragma unroll
      for (int kf = 0; kf < 8; ++kf) {
        short8v kb = *(const short8v*)((const char*)sK + swz(kf * 16 + li, cb));
        s[kf] = mfma16(qa[kk], kb, s[kf]);
      }
    }

    // exp, rowsum partial, attnT store, sP write
#pragma unroll
    for (int kf = 0; kf < 8; ++kf) {
      ushort pb[4];
#pragma unroll
      for (int r = 0; r < 4; ++r) {
        float p = __expf(s[kf][r] * SCALE);
        rs[r] += p;
        pb[r] = f2bf(p);
        int q = w * 16 + lg * 4 + r;
        *(ushort*)((char*)sP + swz256(q, (kf * 16 + li) * 2)) = pb[r];
      }
      int key = ch * CHK + sc * 128 + kf * 16 + li;
      ushort4 pk; pk.x = pb[0]; pk.y = pb[1]; pk.z = pb[2]; pk.w = pb[3];
      *(ushort4*)(attnT + ((size_t)bh * NTOK + key) * 64 + w * 16 + lg * 4) = pk;
    }

    // PV partial accumulate over these 128 keys
#pragma unroll
    for (int kk4 = 0; kk4 < 4; ++kk4) {
      int cb = kk4 * 64 + lg * 16;
      short8v pa = *(const short8v*)((const char*)sP + swz256(w * 16 + li, cb));
#pragma unroll
      for (int nf = 0; nf < 4; ++nf) {
        short8v vb = *(const short8v*)((const char*)sVT + swz256(nf * 16 + li, cb));
        pv[nf] = mfma16(pa, vb, pv[nf]);
      }
    }
  }

#pragma unroll
  for (int r = 0; r < 4; ++r) {
    float v = rs[r];
    for (int mask = 1; mask < 16; mask <<= 1) v += __shfl_xor(v, mask);
    if (li == 0) rsumP[((size_t)bh * NCH + ch) * 64 + w * 16 + lg * 4 + r] = v;
  }
  float* pvdst = pvP + ((size_t)bh * NCH + ch) * 4096;
#pragma unroll
  for (int nf = 0; nf < 4; ++nf)
#pragma unroll
    for (int r = 0; r < 4; ++r)
      pvdst[(w * 16 + lg * 4 + r) * 64 + nf * 16 + li] = pv[nf][r];
}

// ---------------- midm2: chunk-reduce + reph update + self-attn + xd + M2T ----------------
// one block per (b,h); xd stays in LDS; M2T[b,d,h*64+q] = sum_dd xd[q,dd]*tow[d,h*64+dd]
__global__ __launch_bounds__(256) void k_midm2(const float* __restrict__ rep,
                                               const float* __restrict__ pvP,
                                               const float* __restrict__ rsumP,
                                               const float* __restrict__ step_rep,
                                               const float* __restrict__ step_x,
                                               const ushort* __restrict__ tow,
                                               ushort* __restrict__ m2t) {
  __shared__ float sSum[64];
  __shared__ float sRd[4096];
  __shared__ float sR[64 * 65];
  __shared__ float sT[64 * 65];
  __shared__ ushort sXd[4096];   // [64 q][64 dd] swizzled bf16
  const int bh = blockIdx.x;
  const int b = bh >> 3, h = bh & 7;
  const int t = threadIdx.x, w = t >> 6, l = t & 63;
  const int lg = l >> 4, li = l & 15;

  if (t < 64) {
    float v = 0.f;
#pragma unroll
    for (int ch = 0; ch < NCH; ++ch) v += rsumP[((size_t)bh * NCH + ch) * 64 + t];
    sSum[t] = v;
  }
  {
    const float* p = pvP + (size_t)bh * NCH * 4096;
#pragma unroll
    for (int j = 0; j < 16; ++j) {
      int idx = t + 256 * j;
      float sm = 0.f;
#pragma unroll
      for (int ch = 0; ch < NCH; ++ch) sm += p[ch * 4096 + idx];
      sRd[idx] = sm;
    }
  }
  __syncthreads();
  {
    int q = t >> 2, d0 = (t & 3) * 16;
    float srep = step_rep[h];
    float inv = 1.f / sSum[q];
    const float* rp = rep + ((size_t)b * 64 + q) * CDIM + h * DH + d0;
#pragma unroll
    for (int j = 0; j < 16; ++j) sR[q * 65 + d0 + j] = rp[j] + srep * (sRd[q * 64 + d0 + j] * inv);
  }
  __syncthreads();
  {
    int q = t >> 2, jb = (t & 3) * 16;
    float a[16];
#pragma unroll
    for (int j = 0; j < 16; ++j) {
      float accd = 0.f;
      for (int d = 0; d < 64; ++d) accd += sR[q * 65 + d] * sR[(jb + j) * 65 + d];
      a[j] = accd * SCALE;
    }
    float mx = a[0];
#pragma unroll
    for (int j = 1; j < 16; ++j) mx = fmaxf(mx, a[j]);
    mx = fmaxf(mx, __shfl_xor(mx, 1));
    mx = fmaxf(mx, __shfl_xor(mx, 2));
    float sm = 0.f;
#pragma unroll
    for (int j = 0; j < 16; ++j) { a[j] = __expf(a[j] - mx); sm += a[j]; }
    sm += __shfl_xor(sm, 1);
    sm += __shfl_xor(sm, 2);
    float inv = 1.f / sm;
#pragma unroll
    for (int j = 0; j < 16; ++j) sT[q * 65 + jb + j] = a[j] * inv;
  }
  __syncthreads();
  {
    int q = t >> 2, db = (t & 3) * 16;
    float accd[16] = {};
    for (int j = 0; j < 64; ++j) {
      float w2 = sT[q * 65 + j];
#pragma unroll
      for (int d = 0; d < 16; ++d) accd[d] += w2 * sR[j * 65 + db + d];
    }
    float sc = step_x[h] / sSum[q];
    ushort o[16] __attribute__((aligned(16)));
#pragma unroll
    for (int d = 0; d < 16; ++d) o[d] = f2bf(accd[d] * sc);
    *(short8v*)((char*)sXd + swz(q, db * 2)) = *(short8v*)&o[0];
    *(short8v*)((char*)sXd + swz(q, db * 2 + 16)) = *(short8v*)&o[8];
  }
  __syncthreads();
  // m2: wave w covers d rows [w*128,(w+1)*128)
  floatx4 acc[8][4] = {};
#pragma unroll
  for (int kk = 0; kk < 2; ++kk) {
    int dd0 = kk * 32 + lg * 8;
    short8v bf[4];
#pragma unroll
    for (int nf = 0; nf < 4; ++nf)
      bf[nf] = *(const short8v*)((const char*)sXd + swz(nf * 16 + li, dd0 * 2));
#pragma unroll
    for (int m = 0; m < 8; ++m) {
      int d = w * 128 + m * 16 + li;
      short8v af = *(const short8v*)(tow + (size_t)d * CDIM + h * DH + dd0);
#pragma unroll
      for (int nf = 0; nf < 4; ++nf) acc[m][nf] = mfma16(af, bf[nf], acc[m][nf]);
    }
  }
#pragma unroll
  for (int m = 0; m < 8; ++m)
#pragma unroll
    for (int nf = 0; nf < 4; ++nf)
#pragma unroll
      for (int r = 0; r < 4; ++r) {
        int d = w * 128 + m * 16 + lg * 4 + r;
        int hq = h * 64 + nf * 16 + li;
        m2t[((size_t)b * CDIM + d) * CDIM + hq] = f2bf(acc[m][nf][r]);
      }
}

// ---------------- launch ----------------
extern "C" void kernel_launch(void* const* d_in, const int* in_sizes, int n_in,
                              void* d_out, int out_size, void* d_ws, size_t ws_size,
                              hipStream_t stream) {
  const float* x = (const float*)d_in[0];
  const float* proj_w = (const float*)d_in[1];
  const float* step_rep = (const float*)d_in[2];
  const float* step_x = (const float*)d_in[3];
  const float* to_out_w = (const float*)d_in[4];
  const float* to_out_b = (const float*)d_in[5];
  float* out = (float*)d_out;
  char* ws = (char*)d_ws;
  char* ob = (char*)d_out;   // d_out doubles as scratch until gemm3 overwrites it

  // ws layout:
  ushort* bufA = (ushort*)(ws);                  // attnT                  (32 MiB)
  ushort* bufB = (ushort*)(ws + 33554432);       // w bf16 -> M2T overlay  (32 MiB)
  ushort* pw   = (ushort*)(ws + 67108864);       // proj_w bf16 (512 KiB)
  ushort* tow  = (ushort*)(ws + 67633152);       // to_out_w bf16 (512 KiB)
  float*  rep  = (float*)(ws + 68157440);        // pooled rep fp32 (1 MiB)
  // d_out scratch (all dead before gemm3 writes out):
  float*  pvP   = (float*)(ob);                  // PV partials (8.4 MiB)
  ushort* qbf   = (ushort*)(ob + 34603008);      // pre-swizzled Q tiles (512 KiB)
  float*  rsumP = (float*)(ob + 35127296);       // rowsum partials (128 KiB)
  ushort* m2t   = bufB;                          // M2T overlays w after qkexp

  k_f2bfw<<<512, 256, 0, stream>>>(proj_w, to_out_w, pw, tow);

  k_gemm1f<<<1024, 256, 0, stream>>>(x, pw, bufB);

  k_pool<<<Bc * 64, 256, 0, stream>>>(bufB, rep, qbf);

  k_qkexp<<<dim3(NCH, Bc * HEADS), 256, 0, stream>>>(bufB, qbf, bufA, pvP, rsumP);

  k_midm2<<<Bc * HEADS, 256, 0, stream>>>(rep, pvP, rsumP, step_rep, step_x, tow, m2t);

  k_gemm3<<<1024, 256, 0, stream>>>(bufA, m2t, out, to_out_b);
}

// Round 6
// 106.579 us; speedup vs baseline: 2.4320x; 1.0765x over previous
//
#include <hip/hip_runtime.h>
#include <hip/hip_bf16.h>
#include <stdint.h>

// ---------------- common types / helpers ----------------
typedef __attribute__((ext_vector_type(8))) short short8v;   // 8 x bf16 (4 VGPRs)
typedef __attribute__((ext_vector_type(4))) float floatx4;
typedef __attribute__((ext_vector_type(4))) unsigned uintx4;

#define DEV __device__ __forceinline__

DEV ushort f2bf(float f) {                      // RNE float -> bf16 bits
  union { float f; unsigned u; } v; v.f = f;
  unsigned r = v.u + 0x7fffu + ((v.u >> 16) & 1u);
  return (ushort)(r >> 16);
}
DEV float bf2f(ushort b) {
  union { unsigned u; float f; } v; v.u = ((unsigned)b) << 16;
  return v.f;
}
DEV unsigned cvtpk(float lo, float hi) {        // packed f32->bf16 (RNE), 1 inst
  unsigned r;
  asm("v_cvt_pk_bf16_f32 %0, %1, %2" : "=v"(r) : "v"(lo), "v"(hi));
  return r;
}
// XOR swizzle for 64-col bf16 tiles (128B rows)
DEV int swz(int row, int colByte) {
  return row * 128 + (colByte ^ ((row & 7) << 4));
}
// XOR swizzle for 128-col bf16 tiles (256B rows)
DEV int swz256(int row, int colByte) {
  return row * 256 + (colByte ^ ((row & 7) << 4));
}
DEV floatx4 mfma16(short8v a, short8v b, floatx4 c) {
  return __builtin_amdgcn_mfma_f32_16x16x32_bf16(a, b, c, 0, 0, 0);
}

#define GLD_LDS16(g, l)                                                   \
  __builtin_amdgcn_global_load_lds(                                       \
      (const __attribute__((address_space(1))) void*)(g),                 \
      (__attribute__((address_space(3))) void*)(l), 16, 0, 0)

#define WAIT_LGKM0 asm volatile("s_waitcnt lgkmcnt(0)" ::: "memory")
DEV void sbar() {
  __builtin_amdgcn_sched_barrier(0);
  __builtin_amdgcn_s_barrier();
  __builtin_amdgcn_sched_barrier(0);
}

// problem constants
constexpr int Bc = 8, HEADS = 8, NTOK = 4096, CDIM = 512, DH = 64;
constexpr float SCALE = 0.125f;   // DH^-0.5
constexpr int NCH = 8, CHK = 512;    // key chunks for qkexp (4 sub-tiles of 128)

// both weight matrices in one launch (512 blocks x 256 thr, 1 float4 each)
__global__ __launch_bounds__(256) void k_f2bfw(const float* __restrict__ a,
                                               const float* __restrict__ b,
                                               ushort* __restrict__ da,
                                               ushort* __restrict__ db) {
  int i = blockIdx.x * 256 + threadIdx.x;    // 0 .. 131071
  const float* s = (i < 65536) ? a : b;
  ushort* d = (i < 65536) ? da : db;
  int j = i & 65535;
  float4 f = ((const float4*)s)[j];
  ushort4 o;
  o.x = f2bf(f.x); o.y = f2bf(f.y); o.z = f2bf(f.z); o.w = f2bf(f.w);
  ((ushort4*)d)[j] = o;
}

// ================= gemm1: w[M,512] = bf16(x[M,512]) @ pw[512,512]^T =================
// 256x256 tile, BK=64, 8 waves (2m x 4n), double-buffered LDS, reg-staged
// (T14 issue-early/write-late) so loads stay in flight across the barrier.
// fp32 A converted in-register via v_cvt_pk_bf16_f32.
__global__ __launch_bounds__(512, 2) void k_gemm1(const float* __restrict__ A,
                                                  const ushort* __restrict__ Bm,
                                                  ushort* __restrict__ Cout) {
  __shared__ ushort sA[2][256 * 64];
  __shared__ ushort sB[2][256 * 64];
  const int t = threadIdx.x;                 // 0..511
  const int w = t >> 6, l = t & 63;
  const int lg = l >> 4, li = l & 15;
  const int bid = blockIdx.x;                // 256 blocks
  const int f = (bid & 7) * 32 + (bid >> 3); // XCD-chunked: A-panel pairs co-XCD
  const int m0 = (f >> 1) * 256, n0 = (f & 1) * 256;
  const int wr = (w >> 2) * 128, wc = (w & 3) * 64;

  float4 fa[8];     // raw fp32 A for next tile (4 slots x 32B)
  short8v fb[4];    // bf16 B for next tile (4 slots x 16B)

  auto loadA = [&](int kt) {
#pragma unroll
    for (int i = 0; i < 4; ++i) {
      int s = i * 512 + t, row = s >> 3, pch = s & 7;
      const float* g = A + (size_t)(m0 + row) * CDIM + kt * 64 + pch * 8;
      fa[2 * i] = *(const float4*)g;
      fa[2 * i + 1] = *(const float4*)(g + 4);
    }
  };
  auto loadB = [&](int kt) {
#pragma unroll
    for (int i = 0; i < 4; ++i) {
      int s = i * 512 + t, row = s >> 3, pch = s & 7;
      fb[i] = *(const short8v*)(Bm + (size_t)(n0 + row) * CDIM + kt * 64 + pch * 8);
    }
  };
  auto writeAB = [&](int buf) {
#pragma unroll
    for (int i = 0; i < 4; ++i) {
      int s = i * 512 + t, row = s >> 3, pch = s & 7;
      int off = row * 128 + ((pch ^ (row & 7)) << 4);
      uintx4 pk;
      pk.x = cvtpk(fa[2 * i].x, fa[2 * i].y);
      pk.y = cvtpk(fa[2 * i].z, fa[2 * i].w);
      pk.z = cvtpk(fa[2 * i + 1].x, fa[2 * i + 1].y);
      pk.w = cvtpk(fa[2 * i + 1].z, fa[2 * i + 1].w);
      *(uintx4*)((char*)sA[buf] + off) = pk;
      *(short8v*)((char*)sB[buf] + off) = fb[i];
    }
  };

  floatx4 acc[8][4] = {};

  // prologue: stage tile 0, prefetch tile 1 into regs
  loadA(0); loadB(0);
  writeAB(0);
  loadA(1); loadB(1);
  WAIT_LGKM0;
  sbar();

#pragma unroll
  for (int kt = 0; kt < 8; ++kt) {
    const int cur = kt & 1;
    if (kt < 7) writeAB(cur ^ 1);            // ds_write tile kt+1 (regs from prev iter)
    if (kt < 6) { loadA(kt + 2); loadB(kt + 2); }  // in flight across barrier
    // compute tile kt
#pragma unroll
    for (int kk = 0; kk < 2; ++kk) {
      int colb = (kk * 32 + lg * 8) * 2;
      short8v bf[4];
#pragma unroll
      for (int n = 0; n < 4; ++n)
        bf[n] = *(const short8v*)((const char*)sB[cur] + swz(wc + n * 16 + li, colb));
#pragma unroll
      for (int mh = 0; mh < 2; ++mh) {
        short8v af[4];
#pragma unroll
        for (int m = 0; m < 4; ++m)
          af[m] = *(const short8v*)((const char*)sA[cur] + swz(wr + mh * 64 + m * 16 + li, colb));
#pragma unroll
        for (int m = 0; m < 4; ++m)
#pragma unroll
          for (int n = 0; n < 4; ++n)
            acc[mh * 4 + m][n] = mfma16(af[m], bf[n], acc[mh * 4 + m][n]);
      }
    }
    if (kt < 7) { WAIT_LGKM0; sbar(); }
  }

#pragma unroll
  for (int m = 0; m < 8; ++m)
#pragma unroll
    for (int n = 0; n < 4; ++n) {
      int col = n0 + wc + n * 16 + li;
#pragma unroll
      for (int r = 0; r < 4; ++r) {
        int row = m0 + wr + m * 16 + lg * 4 + r;
        Cout[(size_t)row * CDIM + col] = f2bf(acc[m][n][r]);
      }
    }
}

// ================= gemm3: out[b,n,d] = sum_hq attnT[b,h,n,q]*M2T[b,d,hq] + bias =================
// same pipelined 256^2 structure; A,B bf16 reg-staged; b == XCD (L2-local slab).
__global__ __launch_bounds__(512, 2) void k_gemm3(const ushort* __restrict__ attnT, // [b,8,4096,64]
                                                  const ushort* __restrict__ M2T,   // [b,512,512]
                                                  float* __restrict__ out,          // [b,4096,512]
                                                  const float* __restrict__ bias) {
  __shared__ ushort sA[2][256 * 64];
  __shared__ ushort sB[2][256 * 64];
  const int t = threadIdx.x;
  const int w = t >> 6, l = t & 63;
  const int lg = l >> 4, li = l & 15;
  const int bid = blockIdx.x;          // 256
  const int b = bid & 7;               // one batch per XCD
  const int idx = bid >> 3;            // 0..31
  const int m0 = (idx >> 1) * 256, n0 = (idx & 1) * 256;
  const int wr = (w >> 2) * 128, wc = (w & 3) * 64;
  const ushort* Bb = M2T + (size_t)b * 262144;

  short8v fA[4], fB[4];
  auto loadAB = [&](int kt) {
#pragma unroll
    for (int i = 0; i < 4; ++i) {
      int s = i * 512 + t, row = s >> 3, pch = s & 7;
      fA[i] = *(const short8v*)(attnT + (((size_t)(b * 8 + kt)) * NTOK + m0 + row) * 64 + pch * 8);
      fB[i] = *(const short8v*)(Bb + (size_t)(n0 + row) * CDIM + kt * 64 + pch * 8);
    }
  };
  auto writeAB = [&](int buf) {
#pragma unroll
    for (int i = 0; i < 4; ++i) {
      int s = i * 512 + t, row = s >> 3, pch = s & 7;
      int off = row * 128 + ((pch ^ (row & 7)) << 4);
      *(short8v*)((char*)sA[buf] + off) = fA[i];
      *(short8v*)((char*)sB[buf] + off) = fB[i];
    }
  };

  floatx4 acc[8][4] = {};

  loadAB(0);
  writeAB(0);
  loadAB(1);
  WAIT_LGKM0;
  sbar();

#pragma unroll
  for (int kt = 0; kt < 8; ++kt) {
    const int cur = kt & 1;
    if (kt < 7) writeAB(cur ^ 1);
    if (kt < 6) loadAB(kt + 2);
#pragma unroll
    for (int kk = 0; kk < 2; ++kk) {
      int colb = (kk * 32 + lg * 8) * 2;
      short8v bf[4];
#pragma unroll
      for (int n = 0; n < 4; ++n)
        bf[n] = *(const short8v*)((const char*)sB[cur] + swz(wc + n * 16 + li, colb));
#pragma unroll
      for (int mh = 0; mh < 2; ++mh) {
        short8v af[4];
#pragma unroll
        for (int m = 0; m < 4; ++m)
          af[m] = *(const short8v*)((const char*)sA[cur] + swz(wr + mh * 64 + m * 16 + li, colb));
#pragma unroll
        for (int m = 0; m < 4; ++m)
#pragma unroll
          for (int n = 0; n < 4; ++n)
            acc[mh * 4 + m][n] = mfma16(af[m], bf[n], acc[mh * 4 + m][n]);
      }
    }
    if (kt < 7) { WAIT_LGKM0; sbar(); }
  }

#pragma unroll
  for (int m = 0; m < 8; ++m)
#pragma unroll
    for (int n = 0; n < 4; ++n) {
      int col = n0 + wc + n * 16 + li;
      float bv = bias[col];
#pragma unroll
      for (int r = 0; r < 4; ++r) {
        int row = m0 + wr + m * 16 + lg * 4 + r;
        out[((size_t)b * NTOK + row) * CDIM + col] = acc[m][n][r] + bv;
      }
    }
}

// ---------------- adaptive 8x8 pool + pre-swizzled bf16 Q tiles ----------------
__global__ __launch_bounds__(256) void k_pool(const ushort* __restrict__ wm,
                                              float* __restrict__ rep,
                                              ushort* __restrict__ qbf) {
  const int blk = blockIdx.x;      // b*64 + qi
  const int b = blk >> 6, qi = blk & 63;
  const int ph = qi >> 3, pw = qi & 7;
  const int c0 = threadIdx.x * 2;
  float a0 = 0.f, a1 = 0.f;
  for (int u = 0; u < 64; ++u) {
    int n = (ph * 8 + (u >> 3)) * 64 + pw * 8 + (u & 7);
    unsigned v = *(const unsigned*)(wm + ((size_t)b * NTOK + n) * CDIM + c0);
    a0 += bf2f((ushort)(v & 0xffff));
    a1 += bf2f((ushort)(v >> 16));
  }
  a0 *= 0.015625f; a1 *= 0.015625f;
  float* dst = rep + ((size_t)b * 64 + qi) * CDIM + c0;
  dst[0] = a0;
  dst[1] = a1;
  // bf16 Q tile, swizzled layout per (b,h): [64 q][64 d]
  int h = c0 >> 6, d0 = c0 & 63;   // d0 even
  unsigned pack = (unsigned)f2bf(a0) | ((unsigned)f2bf(a1) << 16);
  *(unsigned*)((char*)qbf + ((size_t)(b * 8 + h)) * 8192 + swz(qi, d0 * 2)) = pack;
}

// ---------------- qkexp: per (bh, chunk of 512 keys; 4 sub-tiles of 128) ----------------
__global__ __launch_bounds__(256) void k_qkexp(const ushort* __restrict__ wmat,
                                               const ushort* __restrict__ qbf,
                                               ushort* __restrict__ attnT,  // [bh,4096,64]
                                               float* __restrict__ pvP,     // [bh,8,64,64]
                                               float* __restrict__ rsumP) { // [bh,8,64]
  __shared__ char smem[57344] __attribute__((aligned(128)));
  ushort* sQ  = (ushort*)smem;            // [64 q][64 d]   8KB swizzled
  ushort* sK  = (ushort*)(smem + 8192);   // [128 n][64 d] 16KB swizzled
  ushort* sVT = (ushort*)(smem + 24576);  // [64 d][128 n] 16KB swizzled (256B rows)
  ushort* sP  = (ushort*)(smem + 40960);  // [64 q][128 k] 16KB swizzled (256B rows)

  const int bh = blockIdx.y, ch = blockIdx.x;
  const int b = bh >> 3, h = bh & 7;
  const int t = threadIdx.x, w = t >> 6, l = t & 63;
  const int lg = l >> 4, li = l & 15;

  // stage Q (pre-swizzled in qbf -> linear copy)
  {
    const char* qsrc = (const char*)(qbf + (size_t)bh * 4096);
#pragma unroll
    for (int i = 0; i < 2; ++i) {
      int flat = i * 256 + t;
      GLD_LDS16(qsrc + flat * 16, (char*)sQ + flat * 16);
    }
  }

  float rs[4] = {};
  floatx4 pv[4] = {};
  short8v qa[2];
  bool qaLoaded = false;

  for (int sc = 0; sc < 4; ++sc) {
    const ushort* wbase = wmat + ((size_t)b * NTOK + ch * CHK + sc * 128) * CDIM + h * DH;
    __syncthreads();
    // stage K tile (source pre-swizzled)
#pragma unroll
    for (int i = 0; i < 4; ++i) {
      int flat = i * 256 + t;
      int row = flat >> 3, pch = flat & 7;
      int sch = pch ^ (row & 7);
      GLD_LDS16(wbase + (size_t)row * CDIM + sch * 8, (char*)sK + flat * 16);
    }
    // stage V transposed: [d][n] — packed u32 writes (n-pair per thread)
    {
      int u = t & 63;                 // n-pair: columns 2u, 2u+1
      int dh2 = (t >> 6) * 16;        // 16 d's
      const ushort* g0 = wbase + (size_t)(2 * u) * CDIM + dh2;
      const ushort* g1 = g0 + CDIM;
      short8v a0 = *(const short8v*)g0;
      short8v a1 = *(const short8v*)(g0 + 8);
      short8v b0 = *(const short8v*)g1;
      short8v b1 = *(const short8v*)(g1 + 8);
#pragma unroll
      for (int j = 0; j < 8; ++j) {
        unsigned w0 = ((unsigned)(ushort)a0[j]) | (((unsigned)(ushort)b0[j]) << 16);
        *(unsigned*)((char*)sVT + swz256(dh2 + j, 4 * u)) = w0;
        unsigned w1 = ((unsigned)(ushort)a1[j]) | (((unsigned)(ushort)b1[j]) << 16);
        *(unsigned*)((char*)sVT + swz256(dh2 + 8 + j, 4 * u)) = w1;
      }
    }
    __syncthreads();

    if (!qaLoaded) {
      qaLoaded = true;
#pragma unroll
      for (int kk = 0; kk < 2; ++kk)
        qa[kk] = *(const short8v*)((const char*)sQ + swz(w * 16 + li, (kk * 32 + lg * 8) * 2));
    }

    // QK^T
    floatx4 s[8] = {};
#pragma unroll
    for (int kk = 0; kk < 2; ++kk) {
      int cb = (kk * 32 + lg * 8) * 2;
#pragma unroll
      for (int kf = 0; kf < 8; ++kf) {
        short8v kb = *(const short8v*)((const char*)sK + swz(kf * 16 + li, cb));
        s[kf] = mfma16(qa[kk], kb, s[kf]);
      }
    }

    // exp, rowsum partial, attnT store, sP write
#pragma unroll
    for (int kf = 0; kf < 8; ++kf) {
      ushort pb[4];
#pragma unroll
      for (int r = 0; r < 4; ++r) {
        float p = __expf(s[kf][r] * SCALE);
        rs[r] += p;
        pb[r] = f2bf(p);
        int q = w * 16 + lg * 4 + r;
        *(ushort*)((char*)sP + swz256(q, (kf * 16 + li) * 2)) = pb[r];
      }
      int key = ch * CHK + sc * 128 + kf * 16 + li;
      ushort4 pk; pk.x = pb[0]; pk.y = pb[1]; pk.z = pb[2]; pk.w = pb[3];
      *(ushort4*)(attnT + ((size_t)bh * NTOK + key) * 64 + w * 16 + lg * 4) = pk;
    }

    // PV partial accumulate over these 128 keys
#pragma unroll
    for (int kk4 = 0; kk4 < 4; ++kk4) {
      int cb = kk4 * 64 + lg * 16;
      short8v pa = *(const short8v*)((const char*)sP + swz256(w * 16 + li, cb));
#pragma unroll
      for (int nf = 0; nf < 4; ++nf) {
        short8v vb = *(const short8v*)((const char*)sVT + swz256(nf * 16 + li, cb));
        pv[nf] = mfma16(pa, vb, pv[nf]);
      }
    }
  }

#pragma unroll
  for (int r = 0; r < 4; ++r) {
    float v = rs[r];
    for (int mask = 1; mask < 16; mask <<= 1) v += __shfl_xor(v, mask);
    if (li == 0) rsumP[((size_t)bh * NCH + ch) * 64 + w * 16 + lg * 4 + r] = v;
  }
  float* pvdst = pvP + ((size_t)bh * NCH + ch) * 4096;
#pragma unroll
  for (int nf = 0; nf < 4; ++nf)
#pragma unroll
    for (int r = 0; r < 4; ++r)
      pvdst[(w * 16 + lg * 4 + r) * 64 + nf * 16 + li] = pv[nf][r];
}

// ---------------- midm2: chunk-reduce + reph update + self-attn + xd + M2T ----------------
__global__ __launch_bounds__(256) void k_midm2(const float* __restrict__ rep,
                                               const float* __restrict__ pvP,
                                               const float* __restrict__ rsumP,
                                               const float* __restrict__ step_rep,
                                               const float* __restrict__ step_x,
                                               const ushort* __restrict__ tow,
                                               ushort* __restrict__ m2t) {
  __shared__ float sSum[64];
  __shared__ float sRd[4096];
  __shared__ float sR[64 * 65];
  __shared__ float sT[64 * 65];
  __shared__ ushort sXd[4096];   // [64 q][64 dd] swizzled bf16
  const int bh = blockIdx.x;
  const int b = bh >> 3, h = bh & 7;
  const int t = threadIdx.x, w = t >> 6, l = t & 63;
  const int lg = l >> 4, li = l & 15;

  if (t < 64) {
    float v = 0.f;
#pragma unroll
    for (int ch = 0; ch < NCH; ++ch) v += rsumP[((size_t)bh * NCH + ch) * 64 + t];
    sSum[t] = v;
  }
  {
    const float* p = pvP + (size_t)bh * NCH * 4096;
#pragma unroll
    for (int j = 0; j < 16; ++j) {
      int idx = t + 256 * j;
      float sm = 0.f;
#pragma unroll
      for (int ch = 0; ch < NCH; ++ch) sm += p[ch * 4096 + idx];
      sRd[idx] = sm;
    }
  }
  __syncthreads();
  {
    int q = t >> 2, d0 = (t & 3) * 16;
    float srep = step_rep[h];
    float inv = 1.f / sSum[q];
    const float* rp = rep + ((size_t)b * 64 + q) * CDIM + h * DH + d0;
#pragma unroll
    for (int j = 0; j < 16; ++j) sR[q * 65 + d0 + j] = rp[j] + srep * (sRd[q * 64 + d0 + j] * inv);
  }
  __syncthreads();
  {
    int q = t >> 2, jb = (t & 3) * 16;
    float a[16];
#pragma unroll
    for (int j = 0; j < 16; ++j) {
      float accd = 0.f;
      for (int d = 0; d < 64; ++d) accd += sR[q * 65 + d] * sR[(jb + j) * 65 + d];
      a[j] = accd * SCALE;
    }
    float mx = a[0];
#pragma unroll
    for (int j = 1; j < 16; ++j) mx = fmaxf(mx, a[j]);
    mx = fmaxf(mx, __shfl_xor(mx, 1));
    mx = fmaxf(mx, __shfl_xor(mx, 2));
    float sm = 0.f;
#pragma unroll
    for (int j = 0; j < 16; ++j) { a[j] = __expf(a[j] - mx); sm += a[j]; }
    sm += __shfl_xor(sm, 1);
    sm += __shfl_xor(sm, 2);
    float inv = 1.f / sm;
#pragma unroll
    for (int j = 0; j < 16; ++j) sT[q * 65 + jb + j] = a[j] * inv;
  }
  __syncthreads();
  {
    int q = t >> 2, db = (t & 3) * 16;
    float accd[16] = {};
    for (int j = 0; j < 64; ++j) {
      float w2 = sT[q * 65 + j];
#pragma unroll
      for (int d = 0; d < 16; ++d) accd[d] += w2 * sR[j * 65 + db + d];
    }
    float sc = step_x[h] / sSum[q];
    ushort o[16] __attribute__((aligned(16)));
#pragma unroll
    for (int d = 0; d < 16; ++d) o[d] = f2bf(accd[d] * sc);
    *(short8v*)((char*)sXd + swz(q, db * 2)) = *(short8v*)&o[0];
    *(short8v*)((char*)sXd + swz(q, db * 2 + 16)) = *(short8v*)&o[8];
  }
  __syncthreads();
  // m2: wave w covers d rows [w*128,(w+1)*128)
  floatx4 acc[8][4] = {};
#pragma unroll
  for (int kk = 0; kk < 2; ++kk) {
    int dd0 = kk * 32 + lg * 8;
    short8v bf[4];
#pragma unroll
    for (int nf = 0; nf < 4; ++nf)
      bf[nf] = *(const short8v*)((const char*)sXd + swz(nf * 16 + li, dd0 * 2));
#pragma unroll
    for (int m = 0; m < 8; ++m) {
      int d = w * 128 + m * 16 + li;
      short8v af = *(const short8v*)(tow + (size_t)d * CDIM + h * DH + dd0);
#pragma unroll
      for (int nf = 0; nf < 4; ++nf) acc[m][nf] = mfma16(af, bf[nf], acc[m][nf]);
    }
  }
#pragma unroll
  for (int m = 0; m < 8; ++m)
#pragma unroll
    for (int nf = 0; nf < 4; ++nf)
#pragma unroll
      for (int r = 0; r < 4; ++r) {
        int d = w * 128 + m * 16 + lg * 4 + r;
        int hq = h * 64 + nf * 16 + li;
        m2t[((size_t)b * CDIM + d) * CDIM + hq] = f2bf(acc[m][nf][r]);
      }
}

// ---------------- launch ----------------
extern "C" void kernel_launch(void* const* d_in, const int* in_sizes, int n_in,
                              void* d_out, int out_size, void* d_ws, size_t ws_size,
                              hipStream_t stream) {
  const float* x = (const float*)d_in[0];
  const float* proj_w = (const float*)d_in[1];
  const float* step_rep = (const float*)d_in[2];
  const float* step_x = (const float*)d_in[3];
  const float* to_out_w = (const float*)d_in[4];
  const float* to_out_b = (const float*)d_in[5];
  float* out = (float*)d_out;
  char* ws = (char*)d_ws;
  char* ob = (char*)d_out;   // d_out doubles as scratch until gemm3 overwrites it

  // ws layout:
  ushort* bufA = (ushort*)(ws);                  // attnT                  (32 MiB)
  ushort* bufB = (ushort*)(ws + 33554432);       // w bf16 -> M2T overlay  (32 MiB)
  ushort* pw   = (ushort*)(ws + 67108864);       // proj_w bf16 (512 KiB)
  ushort* tow  = (ushort*)(ws + 67633152);       // to_out_w bf16 (512 KiB)
  float*  rep  = (float*)(ws + 68157440);        // pooled rep fp32 (1 MiB)
  // d_out scratch (all dead before gemm3 writes out):
  float*  pvP   = (float*)(ob);                  // PV partials (8.4 MiB)
  ushort* qbf   = (ushort*)(ob + 34603008);      // pre-swizzled Q tiles (512 KiB)
  float*  rsumP = (float*)(ob + 35127296);       // rowsum partials (128 KiB)
  ushort* m2t   = bufB;                          // M2T overlays w after qkexp

  k_f2bfw<<<512, 256, 0, stream>>>(proj_w, to_out_w, pw, tow);

  k_gemm1<<<256, 512, 0, stream>>>(x, pw, bufB);

  k_pool<<<Bc * 64, 256, 0, stream>>>(bufB, rep, qbf);

  k_qkexp<<<dim3(NCH, Bc * HEADS), 256, 0, stream>>>(bufB, qbf, bufA, pvP, rsumP);

  k_midm2<<<Bc * HEADS, 256, 0, stream>>>(rep, pvP, rsumP, step_rep, step_x, tow, m2t);

  k_gemm3<<<256, 512, 0, stream>>>(bufA, m2t, out, to_out_b);
}